// Round 3
// baseline (456.064 us; speedup 1.0000x reference)
//
#include <hip/hip_runtime.h>
#include <hip/hip_bf16.h>
#include <stdint.h>

#define B_  4
#define S_  2048
#define D_  1024
#define H_  16
#define DK_ 64
#define M_  (B_*S_)                 // 8192
#define MD_ ((size_t)M_*D_)         // 8388608

typedef unsigned short u16;
typedef unsigned int   u32;
using bh8 = __attribute__((ext_vector_type(8))) short;
using fx4 = __attribute__((ext_vector_type(4))) float;
using us4 = __attribute__((ext_vector_type(4))) unsigned short;

#define C1_ 0.18033688011112042f    // (1/sqrt(64)) * log2(e)

__device__ __forceinline__ u16 f2bf(float f){
  union { float f; u32 u; } v; v.f = f;
  u32 r = v.u + 0x7FFFu + ((v.u >> 16) & 1u);
  return (u16)(r >> 16);
}
__device__ __forceinline__ u16 f2bf_fast(float f){
  union { float f; u32 u; } v; v.f = f;
  return (u16)((v.u + 0x8000u) >> 16);
}
__device__ __forceinline__ float fexp2(float x){
  float r;
  asm("v_exp_f32 %0, %1\n\ts_nop 0" : "=v"(r) : "v"(x));
  return r;
}
// async global->LDS, 16B/lane; LDS dest = wave-uniform base + lane*16
__device__ __forceinline__ void gl16(const void* g, void* l){
  __builtin_amdgcn_global_load_lds(
      (const __attribute__((address_space(1))) unsigned int*)g,
      (__attribute__((address_space(3))) unsigned int*)l, 16, 0, 0);
}

// ---------- 4x transpose+convert; z==0 (Wq) pre-scaled by C1_ ----------
__global__ __launch_bounds__(256) void transpose4_k(const float* __restrict__ W0,
                                                    const float* __restrict__ W1,
                                                    const float* __restrict__ W2,
                                                    const float* __restrict__ W3,
                                                    u16* __restrict__ out){
  int z = blockIdx.z;
  const float* in = (z==0)? W0 : (z==1)? W1 : (z==2)? W2 : W3;
  float scale = (z==0)? C1_ : 1.0f;
  u16* o = out + (size_t)z*1024*1024;
  __shared__ u16 tile[32][33];
  int tx = threadIdx.x, ty = threadIdx.y;
  int x0 = blockIdx.x*32, y0 = blockIdx.y*32;
  #pragma unroll
  for (int j=0;j<32;j+=8) tile[ty+j][tx] = f2bf(in[(size_t)(y0+ty+j)*D_ + x0+tx]*scale);
  __syncthreads();
  #pragma unroll
  for (int j=0;j<32;j+=8) o[(size_t)(x0+ty+j)*D_ + y0+tx] = tile[tx][ty+j];
}

// ---------- fp32 -> bf16 convert; z selects (src,dst) of 3 ----------
__global__ __launch_bounds__(256) void cvt3_k(const float* __restrict__ s0,
                                              const float* __restrict__ s1,
                                              const float* __restrict__ s2,
                                              u16* __restrict__ d0,
                                              u16* __restrict__ d1,
                                              u16* __restrict__ d2, int n8){
  int z = blockIdx.z;
  const float* in = (z==0)? s0 : (z==1)? s1 : s2;
  u16* out = (z==0)? d0 : (z==1)? d1 : d2;
  int i = blockIdx.x*256 + threadIdx.x;
  if (i >= n8) return;
  const float4* p = (const float4*)(in + (size_t)i*8);
  float4 a0 = p[0], a1 = p[1];
  u16 o[8];
  o[0]=f2bf(a0.x); o[1]=f2bf(a0.y); o[2]=f2bf(a0.z); o[3]=f2bf(a0.w);
  o[4]=f2bf(a1.x); o[5]=f2bf(a1.y); o[6]=f2bf(a1.z); o[7]=f2bf(a1.w);
  *(bh8*)(out + (size_t)i*8) = *(bh8*)o;
}

// ---------- C = A @ BT^T, K=N=1024, bf16 in, fp32 accum ----------
// 2-phase double-buffer with COUNTED vmcnt (T4): raw s_barrier (no implicit
// vmcnt(0) drain -- __syncthreads() was draining the prefetch at the bottom
// of every iteration, making R1's "prefetch" dead on arrival; measured
// no-op 139->138.7 us). Per iter: stage(t+1) -> vmcnt(8) (tile-t's own 8
// loads done, tile-t+1's 8 stay in flight across the barrier) -> barrier ->
// ds_read+MFMA -> fence -> barrier (all reads done before next overwrite).
// MODE 1: fp32 C (final O @ Wo).
template<int MODE>
__global__ __launch_bounds__(256) void gemm_bt(const u16* __restrict__ Abase,
                                               const u16* __restrict__ BTbase,
                                               void* __restrict__ Cbase){
  __shared__ __align__(16) u16 Asl[2][128*64];
  __shared__ __align__(16) u16 Bsl[2][128*64];
  int z = blockIdx.z;
  const u16* A  = Abase  + (size_t)z*MD_;
  const u16* BT = BTbase + (size_t)z*1024*1024;
  int tid  = threadIdx.x;
  int w    = tid >> 6, lane = tid & 63, quad = lane >> 4, ln = lane & 15;
  int waveM = w >> 1, waveN = w & 1;
  int rowBase = blockIdx.y*128, colBase = blockIdx.x*128;

  fx4 acc[4][4];
  #pragma unroll
  for (int i=0;i<4;i++)
    #pragma unroll
    for (int j=0;j<4;j++) acc[i][j] = (fx4){0.f,0.f,0.f,0.f};

  auto stage = [&](int k0, int bi){
    #pragma unroll
    for (int i=0;i<4;i++){
      int slot = i*256 + tid;
      int kc = slot >> 7, r = slot & 127;
      gl16(&A [(size_t)(rowBase + r)*D_ + k0 + kc*8], &Asl[bi][slot*8]);
      gl16(&BT[(size_t)(colBase + r)*D_ + k0 + kc*8], &Bsl[bi][slot*8]);
    }
  };

  stage(0, 0);                       // 8 loads in flight

  for (int t = 0; t < 16; ++t){
    int cur = t & 1;
    if (t+1 < 16){
      stage((t+1)*64, cur^1);        // +8 -> 16 in flight
      asm volatile("s_waitcnt vmcnt(8)" ::: "memory");   // tile-t arrived
    } else {
      asm volatile("s_waitcnt vmcnt(0)" ::: "memory");   // final tile
    }
    __builtin_amdgcn_s_barrier();    // all waves' tile-t DMA visible
    asm volatile("" ::: "memory");
    #pragma unroll
    for (int ks=0; ks<2; ks++){
      bh8 af[4], bf[4];
      #pragma unroll
      for (int tt=0;tt<4;tt++){
        af[tt] = *(const bh8*)(&Asl[cur][((ks*4+quad)*128 + waveM*64 + tt*16 + ln)*8]);
        bf[tt] = *(const bh8*)(&Bsl[cur][((ks*4+quad)*128 + waveN*64 + tt*16 + ln)*8]);
      }
      #pragma unroll
      for (int i=0;i<4;i++)
        #pragma unroll
        for (int j=0;j<4;j++)
          acc[i][j] = __builtin_amdgcn_mfma_f32_16x16x32_bf16(af[i], bf[j], acc[i][j], 0, 0, 0);
    }
    asm volatile("" ::: "memory");
    __builtin_amdgcn_s_barrier();    // reads of buf[cur] done; safe to overwrite next iter
  }

  // epilogue: C/D layout col = lane&15, row = quad*4 + reg  [m89/m91-verified]
  #pragma unroll
  for (int i=0;i<4;i++){
    int row0 = rowBase + waveM*64 + i*16 + quad*4;
    #pragma unroll
    for (int j=0;j<4;j++){
      int col = colBase + waveN*64 + j*16 + ln;
      #pragma unroll
      for (int r=0;r<4;r++){
        if (MODE == 1) ((float*)Cbase)[(size_t)(row0 + r)*D_ + col] = acc[i][j][r];
        else ((u16*)Cbase + (size_t)z*MD_)[(size_t)(row0 + r)*D_ + col] = f2bf(acc[i][j][r]);
      }
    }
  }
}

// ---------- fused Q/K/V projection: z=0 -> Qp, z=1 -> Kp, z=2 -> VtG ----------
// Same counted-vmcnt 2-phase loop as gemm_bt.
__global__ __launch_bounds__(256) void gemm_qkv(const u16* __restrict__ Aqk,
                                                const u16* __restrict__ Av,
                                                const u16* __restrict__ WTb,
                                                u16* __restrict__ Cqk,
                                                u16* __restrict__ VtOut){
  __shared__ __align__(16) u16 Asl[2][128*64];
  __shared__ __align__(16) u16 Bsl[2][128*64];
  int z = blockIdx.z;
  const u16* A  = (z < 2) ? (Aqk + (size_t)z*MD_) : Av;
  const u16* BT = WTb + (size_t)z*1024*1024;
  int tid  = threadIdx.x;
  int w    = tid >> 6, lane = tid & 63, quad = lane >> 4, ln = lane & 15;
  int waveM = w >> 1, waveN = w & 1;
  int rowBase = blockIdx.y*128, colBase = blockIdx.x*128;

  fx4 acc[4][4];
  #pragma unroll
  for (int i=0;i<4;i++)
    #pragma unroll
    for (int j=0;j<4;j++) acc[i][j] = (fx4){0.f,0.f,0.f,0.f};

  auto stage = [&](int k0, int bi){
    #pragma unroll
    for (int i=0;i<4;i++){
      int slot = i*256 + tid;
      int kc = slot >> 7, r = slot & 127;
      gl16(&A [(size_t)(rowBase + r)*D_ + k0 + kc*8], &Asl[bi][slot*8]);
      gl16(&BT[(size_t)(colBase + r)*D_ + k0 + kc*8], &Bsl[bi][slot*8]);
    }
  };

  stage(0, 0);

  for (int t = 0; t < 16; ++t){
    int cur = t & 1;
    if (t+1 < 16){
      stage((t+1)*64, cur^1);
      asm volatile("s_waitcnt vmcnt(8)" ::: "memory");
    } else {
      asm volatile("s_waitcnt vmcnt(0)" ::: "memory");
    }
    __builtin_amdgcn_s_barrier();
    asm volatile("" ::: "memory");
    #pragma unroll
    for (int ks=0; ks<2; ks++){
      bh8 af[4], bf[4];
      #pragma unroll
      for (int tt=0;tt<4;tt++){
        af[tt] = *(const bh8*)(&Asl[cur][((ks*4+quad)*128 + waveM*64 + tt*16 + ln)*8]);
        bf[tt] = *(const bh8*)(&Bsl[cur][((ks*4+quad)*128 + waveN*64 + tt*16 + ln)*8]);
      }
      #pragma unroll
      for (int i=0;i<4;i++)
        #pragma unroll
        for (int j=0;j<4;j++)
          acc[i][j] = __builtin_amdgcn_mfma_f32_16x16x32_bf16(af[i], bf[j], acc[i][j], 0, 0, 0);
    }
    asm volatile("" ::: "memory");
    __builtin_amdgcn_s_barrier();
  }

  #pragma unroll
  for (int i=0;i<4;i++){
    int row0 = rowBase + waveM*64 + i*16 + quad*4;
    #pragma unroll
    for (int j=0;j<4;j++){
      int col = colBase + waveN*64 + j*16 + ln;
      if (z == 2){
        // per-head V^T: VtOut[(b*16+h)*64+vd][token]
        int bb = row0 >> 11, tok = row0 & (S_-1);
        int hh = col >> 6,  vd  = col & 63;
        us4 pk;
        #pragma unroll
        for (int r=0;r<4;r++) pk[r] = f2bf(acc[i][j][r]);
        *(us4*)&VtOut[((size_t)((bb*16+hh)*64+vd))*S_ + tok] = pk;
      } else {
        #pragma unroll
        for (int r=0;r<4;r++)
          (Cqk + (size_t)z*MD_)[(size_t)(row0 + r)*D_ + col] = f2bf(acc[i][j][r]);
      }
    }
  }
}

// ---------- flash attention, causal ----------
// Block = 128 q-rows (4 waves x 2 row-groups); k-tile = 64: LDS 40 KB =>
// 4 blocks/CU. K/V double-buffered with prefetch, ONE barrier per tile
// (drain hidden behind long softmax compute). Grid (bh, qtile): XCD = bh%8
// -> per-(b,h) K/V L2 locality; heavy (high qt) dispatch-waves first.
// XOR-swizzled 16B chunk slots (conflict-free, measured
// SQ_LDS_BANK_CONFLICT = 0). O aliases Q (disjoint per block).
__global__ __launch_bounds__(256) void attn_k(const u16* __restrict__ Q,
                                              const u16* __restrict__ Kp,
                                              const u16* __restrict__ VtG,
                                              u16* __restrict__ O){
  __shared__ __align__(16) u16 Kt[2][64*64];    // 2 x 8 KB
  __shared__ __align__(16) u16 Vt[2][64*64];    // 2 x 8 KB
  __shared__ __align__(16) u16 Pb[4*16*64];     // 8 KB

  int bh = blockIdx.x; int b = bh>>4, h = bh&15;
  int qt = (int)gridDim.y - 1 - (int)blockIdx.y;   // heavy dispatch-waves first
  int tid = threadIdx.x;
  int w = tid >> 6, lane = tid & 63, quad = lane >> 4, ln = lane & 15;
  int q0w = qt*128 + w*32;
  size_t headoff = (size_t)h*DK_;

  bh8 qf[2][2];
  #pragma unroll
  for (int rg=0; rg<2; rg++){
    const u16* qp = Q + (size_t)(b*S_ + q0w + rg*16 + ln)*D_ + headoff + quad*8;
    qf[rg][0] = *(const bh8*)qp;
    qf[rg][1] = *(const bh8*)(qp + 32);
  }

  float m_i[2][4], l_i[2][4];
  fx4 oacc[2][4];
  #pragma unroll
  for (int rg=0; rg<2; rg++)
    #pragma unroll
    for (int r=0;r<4;r++){
      m_i[rg][r] = -3e38f; l_i[rg][r] = 0.f;
      oacc[rg][r] = (fx4){0.f,0.f,0.f,0.f};
    }

  auto stage = [&](int k0, int bi){
    #pragma unroll
    for (int i=0;i<2;i++){
      int s = i*256 + tid;
      int n = s >> 3, kc = (s & 7) ^ (n & 7);
      gl16(&Kp[(size_t)(b*S_ + k0 + n)*D_ + headoff + kc*8], &Kt[bi][s*8]);
    }
    #pragma unroll
    for (int i=0;i<2;i++){
      int s = i*256 + tid;
      int vd = s >> 3, c = (s & 7) ^ (vd & 7);
      gl16(&VtG[(size_t)(bh*64 + vd)*S_ + k0 + c*8], &Vt[bi][s*8]);
    }
  };

  u16* Pw = &Pb[w*16*64];
  int ntiles = 2*qt + 2;           // k-tiles of 64 covering [0, (qt+1)*128)

  stage(0, 0);
  __syncthreads();                 // drain prologue staging

  for (int kt=0; kt<ntiles; kt++){
    int cur = kt & 1;
    if (kt+1 < ntiles) stage((kt+1)*64, cur^1);   // prefetch, no wait
    const u16* Kc = Kt[cur];
    const u16* Vc = Vt[cur];
    int k0 = kt*64;
    bool diag = (kt >= 2*qt);      // last two tiles straddle the diagonal

    #pragma unroll
    for (int rg=0; rg<2; rg++){
      // QK^T: 16q x 64k = 4 accs, 2 dk-steps
      fx4 sacc[4];
      #pragma unroll
      for (int t=0;t<4;t++){
        int n = t*16 + ln;
        bh8 kf0 = *(const bh8*)(&Kc[(n*8 + ( quad    ^ (ln&7)))*8]);
        bh8 kf1 = *(const bh8*)(&Kc[(n*8 + ((4+quad) ^ (ln&7)))*8]);
        fx4 zz = (fx4){0.f,0.f,0.f,0.f};
        zz = __builtin_amdgcn_mfma_f32_16x16x32_bf16(qf[rg][0], kf0, zz, 0,0,0);
        zz = __builtin_amdgcn_mfma_f32_16x16x32_bf16(qf[rg][1], kf1, zz, 0,0,0);
        sacc[t] = zz;
      }

      if (diag){
        #pragma unroll
        for (int t=0;t<4;t++){
          int kg = k0 + t*16 + ln;
          #pragma unroll
          for (int r=0;r<4;r++){
            int qg = q0w + rg*16 + quad*4 + r;
            sacc[t][r] = (kg <= qg) ? sacc[t][r] : -3e38f;
          }
        }
      }

      float rowmax[4] = {-3e38f,-3e38f,-3e38f,-3e38f};
      #pragma unroll
      for (int t=0;t<4;t++)
        #pragma unroll
        for (int r=0;r<4;r++) rowmax[r] = fmaxf(rowmax[r], sacc[t][r]);
      #pragma unroll
      for (int r=0;r<4;r++)
        #pragma unroll
        for (int off=1; off<16; off<<=1)
          rowmax[r] = fmaxf(rowmax[r], __shfl_xor(rowmax[r], off, 64));

      float alpha[4], rowsum[4];
      #pragma unroll
      for (int r=0;r<4;r++){
        float mn = fmaxf(m_i[rg][r], rowmax[r]);
        alpha[r] = fexp2(m_i[rg][r] - mn);
        m_i[rg][r] = mn;
        rowsum[r] = 0.f;
      }
      #pragma unroll
      for (int t=0;t<4;t++)
        #pragma unroll
        for (int r=0;r<4;r++){
          float p = fexp2(sacc[t][r] - m_i[rg][r]);
          sacc[t][r] = p;
          rowsum[r] += p;
        }
      #pragma unroll
      for (int r=0;r<4;r++){
        #pragma unroll
        for (int off=1; off<16; off<<=1)
          rowsum[r] += __shfl_xor(rowsum[r], off, 64);
        l_i[rg][r] = l_i[rg][r]*alpha[r] + rowsum[r];
      }
      #pragma unroll
      for (int vt=0;vt<4;vt++)
        #pragma unroll
        for (int r=0;r<4;r++)
          oacc[rg][vt][r] *= alpha[r];

      // P: C-layout -> A-layout via per-wave swizzled LDS (reused across rg)
      #pragma unroll
      for (int t=0;t<4;t++){
        int c = 2*t + (ln>>3), jj = ln & 7;
        #pragma unroll
        for (int r=0;r<4;r++){
          int m = quad*4 + r;
          Pw[(m*8 + (c ^ (m&7)))*8 + jj] = f2bf_fast(sacc[t][r]);
        }
      }
      asm volatile("s_waitcnt lgkmcnt(0)" ::: "memory");

      // PV: 64 keys in 2 chunks, vdim in 4 subtiles
      __builtin_amdgcn_s_setprio(1);
      #pragma unroll
      for (int s2=0; s2<2; s2++){
        int c = s2*4 + quad;
        bh8 pf = *(const bh8*)(&Pw[(ln*8 + (c ^ (ln&7)))*8]);
        #pragma unroll
        for (int vt=0; vt<4; vt++){
          int vd = vt*16 + ln;
          bh8 vf = *(const bh8*)(&Vc[(vd*8 + (c ^ (ln&7)))*8]);
          oacc[rg][vt] = __builtin_amdgcn_mfma_f32_16x16x32_bf16(pf, vf, oacc[rg][vt], 0,0,0);
        }
      }
      __builtin_amdgcn_s_setprio(0);
      asm volatile("s_waitcnt lgkmcnt(0)" ::: "memory");  // drain before Pw reuse
    }
    __syncthreads();   // prefetch arrived (vmcnt drain overlapped compute); buffers safe
  }

  // epilogue: O = acc / l
  #pragma unroll
  for (int rg=0; rg<2; rg++)
    #pragma unroll
    for (int r=0;r<4;r++){
      float linv = 1.0f / l_i[rg][r];
      #pragma unroll
      for (int vt=0; vt<4; vt++){
        float ov = oacc[rg][vt][r] * linv;
        O[(size_t)(b*S_ + q0w + rg*16 + quad*4 + r)*D_ + headoff + vt*16 + ln] = f2bf(ov);
      }
    }
}

extern "C" void kernel_launch(void* const* d_in, const int* in_sizes, int n_in,
                              void* d_out, int out_size, void* d_ws, size_t ws_size,
                              hipStream_t stream){
  const float* q  = (const float*)d_in[0];
  const float* k  = (const float*)d_in[1];
  const float* v  = (const float*)d_in[2];
  const float* Wq = (const float*)d_in[3];
  const float* Wk = (const float*)d_in[4];
  const float* Wv = (const float*)d_in[5];
  const float* Wo = (const float*)d_in[6];
  // d_in[7] = causal mask, statically known -> ignored

  u16* ws  = (u16*)d_ws;
  u16* WT  = ws;                                // 4 x 1M bf16 (Wq*C1, Wk, Wv, Wo)^T
  u16* xa  = WT + (size_t)4*1024*1024;          // q bf16
  u16* xb  = xa + MD_;                          // k bf16
  u16* Qp  = xb + MD_;                          // Q proj (C1-scaled), later O
  u16* Kp  = Qp + MD_;                          // 8 MB + 4*16 MB = 72 MB ws

  // d_out (33.55 MB = 2*MD_ u16) doubles as scratch until the final GEMM:
  u16* vb  = (u16*)d_out;                       // v bf16      [0,   MD_)
  u16* VtG = vb + MD_;                          // per-head V^T [MD_, 2*MD_)

  transpose4_k<<<dim3(32,32,4), dim3(32,8), 0, stream>>>(Wq, Wk, Wv, Wo, WT);

  const int n8 = (int)(MD_/8);
  cvt3_k<<<dim3((n8+255)/256,1,3), 256, 0, stream>>>(q, k, v, xa, xb, vb, n8);

  gemm_qkv<<<dim3(8,64,3), 256, 0, stream>>>(xa, vb, WT, Qp, VtG);  // Qp, Kp, VtG

  attn_k<<<dim3(B_*H_, S_/128), 256, 0, stream>>>(Qp, Kp, VtG, Qp); // O over Q

  gemm_bt<1><<<dim3(8,64,1), 256, 0, stream>>>(Qp, WT + (size_t)3*1024*1024, d_out);
}

// Round 4
// 414.155 us; speedup vs baseline: 1.1012x; 1.1012x over previous
//
#include <hip/hip_runtime.h>
#include <hip/hip_bf16.h>
#include <stdint.h>

#define B_  4
#define S_  2048
#define D_  1024
#define H_  16
#define DK_ 64
#define M_  (B_*S_)                 // 8192
#define MD_ ((size_t)M_*D_)         // 8388608

typedef unsigned short u16;
typedef unsigned int   u32;
using bh8 = __attribute__((ext_vector_type(8))) short;
using fx4 = __attribute__((ext_vector_type(4))) float;
using us4 = __attribute__((ext_vector_type(4))) unsigned short;

#define C1_ 0.18033688011112042f    // (1/sqrt(64)) * log2(e)

__device__ __forceinline__ u16 f2bf(float f){
  union { float f; u32 u; } v; v.f = f;
  u32 r = v.u + 0x7FFFu + ((v.u >> 16) & 1u);
  return (u16)(r >> 16);
}
__device__ __forceinline__ u16 f2bf_fast(float f){
  union { float f; u32 u; } v; v.f = f;
  return (u16)((v.u + 0x8000u) >> 16);
}
__device__ __forceinline__ float fexp2(float x){
  float r;
  asm("v_exp_f32 %0, %1\n\ts_nop 0" : "=v"(r) : "v"(x));
  return r;
}
// async global->LDS, 16B/lane; LDS dest = wave-uniform base + lane*16
__device__ __forceinline__ void gl16(const void* g, void* l){
  __builtin_amdgcn_global_load_lds(
      (const __attribute__((address_space(1))) unsigned int*)g,
      (__attribute__((address_space(3))) unsigned int*)l, 16, 0, 0);
}

// ---------- fused prep: fp32->bf16 cvt (q,k,v) + 4x W transpose ----------
// One launch instead of two (launch gap ~12 us each). Blocks [0,12288):
// cvt z = id>>12; blocks [12288,16384): transpose z = (id-12288)>>10.
__global__ __launch_bounds__(256) void prep_k(const float* __restrict__ q,
                                              const float* __restrict__ k,
                                              const float* __restrict__ v,
                                              const float* __restrict__ W0,
                                              const float* __restrict__ W1,
                                              const float* __restrict__ W2,
                                              const float* __restrict__ W3,
                                              u16* __restrict__ dq,
                                              u16* __restrict__ dk,
                                              u16* __restrict__ dv,
                                              u16* __restrict__ WT){
  int id = blockIdx.x;
  int tid = threadIdx.x;
  if (id < 12288){
    int z = id >> 12;
    int i = (id & 4095)*256 + tid;            // n8 = 4096*256 exactly
    const float* in = (z==0)? q : (z==1)? k : v;
    u16* out = (z==0)? dq : (z==1)? dk : dv;
    const float4* p = (const float4*)(in + (size_t)i*8);
    float4 a0 = p[0], a1 = p[1];
    u16 o[8];
    o[0]=f2bf(a0.x); o[1]=f2bf(a0.y); o[2]=f2bf(a0.z); o[3]=f2bf(a0.w);
    o[4]=f2bf(a1.x); o[5]=f2bf(a1.y); o[6]=f2bf(a1.z); o[7]=f2bf(a1.w);
    *(bh8*)(out + (size_t)i*8) = *(bh8*)o;
  } else {
    int id2 = id - 12288;
    int z = id2 >> 10, b2 = id2 & 1023;
    int bx = b2 & 31, by = b2 >> 5;
    const float* in = (z==0)? W0 : (z==1)? W1 : (z==2)? W2 : W3;
    float scale = (z==0)? C1_ : 1.0f;
    u16* o = WT + (size_t)z*1024*1024;
    __shared__ u16 tile[32][33];
    int tx = tid & 31, ty = tid >> 5;         // 32 x 8
    int x0 = bx*32, y0 = by*32;
    #pragma unroll
    for (int j=0;j<32;j+=8) tile[ty+j][tx] = f2bf(in[(size_t)(y0+ty+j)*D_ + x0+tx]*scale);
    __syncthreads();
    #pragma unroll
    for (int j=0;j<32;j+=8) o[(size_t)(x0+ty+j)*D_ + y0+tx] = tile[tx][ty+j];
  }
}

// ---------- C = A @ BT^T, K=N=1024, 128x128 tile, 2-phase dbuf ----------
// R2-verified form (__syncthreads dbuf; best measured for the 128-block
// final GEMM where 256^2 tiles would leave half the machine idle).
// MODE 1: fp32 C (final O @ Wo).
template<int MODE>
__global__ __launch_bounds__(256) void gemm_bt(const u16* __restrict__ Abase,
                                               const u16* __restrict__ BTbase,
                                               void* __restrict__ Cbase){
  __shared__ __align__(16) u16 Asl[2][128*64];
  __shared__ __align__(16) u16 Bsl[2][128*64];
  int z = blockIdx.z;
  const u16* A  = Abase  + (size_t)z*MD_;
  const u16* BT = BTbase + (size_t)z*1024*1024;
  int tid  = threadIdx.x;
  int w    = tid >> 6, lane = tid & 63, quad = lane >> 4, ln = lane & 15;
  int waveM = w >> 1, waveN = w & 1;
  int rowBase = blockIdx.y*128, colBase = blockIdx.x*128;

  fx4 acc[4][4];
  #pragma unroll
  for (int i=0;i<4;i++)
    #pragma unroll
    for (int j=0;j<4;j++) acc[i][j] = (fx4){0.f,0.f,0.f,0.f};

  auto stage = [&](int k0, int bi){
    #pragma unroll
    for (int i=0;i<4;i++){
      int slot = i*256 + tid;
      int kc = slot >> 7, r = slot & 127;
      gl16(&A [(size_t)(rowBase + r)*D_ + k0 + kc*8], &Asl[bi][slot*8]);
      gl16(&BT[(size_t)(colBase + r)*D_ + k0 + kc*8], &Bsl[bi][slot*8]);
    }
  };

  stage(0, 0);
  __syncthreads();

  for (int t = 0; t < 16; ++t){
    int cur = t & 1;
    if (t+1 < 16) stage((t+1)*64, cur^1);
    #pragma unroll
    for (int ks=0; ks<2; ks++){
      bh8 af[4], bf[4];
      #pragma unroll
      for (int tt=0;tt<4;tt++){
        af[tt] = *(const bh8*)(&Asl[cur][((ks*4+quad)*128 + waveM*64 + tt*16 + ln)*8]);
        bf[tt] = *(const bh8*)(&Bsl[cur][((ks*4+quad)*128 + waveN*64 + tt*16 + ln)*8]);
      }
      #pragma unroll
      for (int i=0;i<4;i++)
        #pragma unroll
        for (int j=0;j<4;j++)
          acc[i][j] = __builtin_amdgcn_mfma_f32_16x16x32_bf16(af[i], bf[j], acc[i][j], 0, 0, 0);
    }
    __syncthreads();
  }

  #pragma unroll
  for (int i=0;i<4;i++){
    int row0 = rowBase + waveM*64 + i*16 + quad*4;
    #pragma unroll
    for (int j=0;j<4;j++){
      int col = colBase + waveN*64 + j*16 + ln;
      #pragma unroll
      for (int r=0;r<4;r++){
        if (MODE == 1) ((float*)Cbase)[(size_t)(row0 + r)*D_ + col] = acc[i][j][r];
        else ((u16*)Cbase + (size_t)z*MD_)[(size_t)(row0 + r)*D_ + col] = f2bf(acc[i][j][r]);
      }
    }
  }
}

// ---------- fused Q/K/V projection: 256x256 tile, BK=64, 8-phase ----------
// T3+T4 port (the 128^2 2-phase plateaued at ~370 TF for this shape; R3's
// counted-vmcnt-at-depth-1 regressed). 512 thr = 8 waves (2M x 4N), per-wave
// C = 128x64 (acc[8][4]). LDS 128 KiB: [buf][half][kc:8][row:128][8] per
// matrix, kc-major (measured conflict-free). Phase q of a tile computes
// M-frags {2q,2q+1} x all 4 N-frags x K=64 = 16 MFMA; B-frags read once at
// q==0 (8 ds_read_b128), A-frags 4/phase.
// Staging schedule (iter = tiles t,t+1; t even; buf = tile&1):
//   ph0/1: A(t+1) lo/hi   [buf1.A last read prev-iter ph7, lgkm'd]
//   ph2/3: B(t+2) lo/hi   [buf0.B read only at ph0, lgkm'd]
//   ph4/5: A(t+2) lo/hi   [buf0.A fully read by ph3]
//   ph6/7: B(t+3) lo/hi   [buf1.B read only at ph4]
// Gates (counted, FIFO retire): vmcnt(4) at ph3 (retires B(t+1)+A(t+1),
// leaves B(t+2) in flight) and ph7 (retires A(t+2), leaves B(t+3));
// tail iter uses vmcnt(0) at ph3. Explicit lgkmcnt(0) after the mid
// barrier guarantees every phase's ds_reads materialize before the end
// barrier, so the next phase's re-stage of that region is safe.
__global__ __launch_bounds__(512, 2) void gemm_qkv8(const u16* __restrict__ Aqk,
                                                    const u16* __restrict__ Av,
                                                    const u16* __restrict__ WTb,
                                                    u16* __restrict__ Cqk,
                                                    u16* __restrict__ VtOut){
  __shared__ __align__(16) u16 AL[2][2][8192];   // 64 KB
  __shared__ __align__(16) u16 BL[2][2][8192];   // 64 KB
  int z = blockIdx.z;
  const u16* A  = (z < 2) ? (Aqk + (size_t)z*MD_) : Av;
  const u16* BT = WTb + (size_t)z*1024*1024;
  int tid = threadIdx.x;
  int w = tid >> 6, lane = tid & 63, quad = lane >> 4, ln = lane & 15;
  int wm = w >> 2, wn = w & 3;
  int rowBase = blockIdx.y*256, colBase = blockIdx.x*256;

  // stage one half-tile (128 rows x 64 k) of A (mat=0) or BT (mat=1)
  auto stageHT = [&](int mat, int kt, int hf){
    int buf = kt & 1;
    u16* dst = mat ? &BL[buf][hf][0] : &AL[buf][hf][0];
    const u16* src = mat ? BT : A;
    int gbase = (mat ? colBase : rowBase) + hf*128;
    int k0 = kt*64;
    #pragma unroll
    for (int j=0;j<2;j++){
      int slot = j*512 + tid;
      int kc = slot >> 7, r = slot & 127;
      gl16(&src[(size_t)(gbase + r)*D_ + k0 + kc*8], dst + slot*8);
    }
  };

  fx4 acc[8][4];
  #pragma unroll
  for (int i=0;i<8;i++)
    #pragma unroll
    for (int j=0;j<4;j++) acc[i][j] = (fx4){0.f,0.f,0.f,0.f};

  // prologue: tile0 (A,B) + B(1); gate leaves B(1) in flight
  stageHT(0,0,0); stageHT(0,0,1);
  stageHT(1,0,0); stageHT(1,0,1);
  stageHT(1,1,0); stageHT(1,1,1);
  asm volatile("s_waitcnt vmcnt(4)" ::: "memory");
  __builtin_amdgcn_s_barrier();

  bh8 bfr[4][2];
  for (int it = 0; it < 8; ++it){
    int t = 2*it;
    #pragma unroll
    for (int p = 0; p < 8; ++p){
      const int buf = p >> 2;          // t even: ph0-3 buf0 (tile t), ph4-7 buf1 (t+1)
      const int q = p & 3;
      const u16* Ah = &AL[buf][wm][0];
      const u16* Bh = &BL[buf][wn>>1][0];

      // ds-reads for this phase
      if (q == 0){
        #pragma unroll
        for (int n=0;n<4;n++)
          #pragma unroll
          for (int ks=0;ks<2;ks++)
            bfr[n][ks] = *(const bh8*)(&Bh[((ks*4+quad)*128 + (wn&1)*64 + n*16 + ln)*8]);
      }
      bh8 af[2][2];
      #pragma unroll
      for (int mi=0;mi<2;mi++)
        #pragma unroll
        for (int ks=0;ks<2;ks++)
          af[mi][ks] = *(const bh8*)(&Ah[((ks*4+quad)*128 + (q*2+mi)*16 + ln)*8]);

      // stage one half-tile (see schedule above)
      switch(p){
        case 0: stageHT(0, t+1, 0); break;
        case 1: stageHT(0, t+1, 1); break;
        case 2: if (t+2 < 16) stageHT(1, t+2, 0); break;
        case 3: if (t+2 < 16) stageHT(1, t+2, 1); break;
        case 4: if (t+2 < 16) stageHT(0, t+2, 0); break;
        case 5: if (t+2 < 16) stageHT(0, t+2, 1); break;
        case 6: if (t+3 < 16) stageHT(1, t+3, 0); break;
        case 7: if (t+3 < 16) stageHT(1, t+3, 1); break;
      }

      // counted gates, once per K-tile
      if (p == 3){
        if (t+2 < 16) asm volatile("s_waitcnt vmcnt(4)" ::: "memory");
        else          asm volatile("s_waitcnt vmcnt(0)" ::: "memory");
      }
      if (p == 7 && t+2 < 16) asm volatile("s_waitcnt vmcnt(4)" ::: "memory");

      __builtin_amdgcn_s_barrier();
      asm volatile("s_waitcnt lgkmcnt(0)" ::: "memory");  // reads materialized

      __builtin_amdgcn_s_setprio(1);
      #pragma unroll
      for (int mi=0;mi<2;mi++)
        #pragma unroll
        for (int n=0;n<4;n++)
          #pragma unroll
          for (int ks=0;ks<2;ks++)
            acc[q*2+mi][n] = __builtin_amdgcn_mfma_f32_16x16x32_bf16(
                                af[mi][ks], bfr[n][ks], acc[q*2+mi][n], 0,0,0);
      __builtin_amdgcn_s_setprio(0);
      __builtin_amdgcn_s_barrier();    // phase closed; next phase may re-stage
    }
  }

  // epilogue: C/D layout col = lane&15, row = quad*4 + reg
  #pragma unroll
  for (int m=0;m<8;m++){
    int row0 = rowBase + wm*128 + m*16 + quad*4;
    #pragma unroll
    for (int n=0;n<4;n++){
      int col = colBase + wn*64 + n*16 + ln;
      if (z == 2){
        int bb = row0 >> 11, tok = row0 & (S_-1);
        int hh = col >> 6,  vd  = col & 63;
        us4 pk;
        #pragma unroll
        for (int r=0;r<4;r++) pk[r] = f2bf(acc[m][n][r]);
        *(us4*)&VtOut[((size_t)((bb*16+hh)*64+vd))*S_ + tok] = pk;
      } else {
        #pragma unroll
        for (int r=0;r<4;r++)
          (Cqk + (size_t)z*MD_)[(size_t)(row0 + r)*D_ + col] = f2bf(acc[m][n][r]);
      }
    }
  }
}

// ---------- flash attention, causal (unchanged from R1) ----------
__global__ __launch_bounds__(256) void attn_k(const u16* __restrict__ Q,
                                              const u16* __restrict__ Kp,
                                              const u16* __restrict__ VtG,
                                              u16* __restrict__ O){
  __shared__ __align__(16) u16 Kt[2][64*64];    // 2 x 8 KB
  __shared__ __align__(16) u16 Vt[2][64*64];    // 2 x 8 KB
  __shared__ __align__(16) u16 Pb[4*16*64];     // 8 KB

  int bh = blockIdx.x; int b = bh>>4, h = bh&15;
  int qt = (int)gridDim.y - 1 - (int)blockIdx.y;   // heavy dispatch-waves first
  int tid = threadIdx.x;
  int w = tid >> 6, lane = tid & 63, quad = lane >> 4, ln = lane & 15;
  int q0w = qt*128 + w*32;
  size_t headoff = (size_t)h*DK_;

  bh8 qf[2][2];
  #pragma unroll
  for (int rg=0; rg<2; rg++){
    const u16* qp = Q + (size_t)(b*S_ + q0w + rg*16 + ln)*D_ + headoff + quad*8;
    qf[rg][0] = *(const bh8*)qp;
    qf[rg][1] = *(const bh8*)(qp + 32);
  }

  float m_i[2][4], l_i[2][4];
  fx4 oacc[2][4];
  #pragma unroll
  for (int rg=0; rg<2; rg++)
    #pragma unroll
    for (int r=0;r<4;r++){
      m_i[rg][r] = -3e38f; l_i[rg][r] = 0.f;
      oacc[rg][r] = (fx4){0.f,0.f,0.f,0.f};
    }

  auto stage = [&](int k0, int bi){
    #pragma unroll
    for (int i=0;i<2;i++){
      int s = i*256 + tid;
      int n = s >> 3, kc = (s & 7) ^ (n & 7);
      gl16(&Kp[(size_t)(b*S_ + k0 + n)*D_ + headoff + kc*8], &Kt[bi][s*8]);
    }
    #pragma unroll
    for (int i=0;i<2;i++){
      int s = i*256 + tid;
      int vd = s >> 3, c = (s & 7) ^ (vd & 7);
      gl16(&VtG[(size_t)(bh*64 + vd)*S_ + k0 + c*8], &Vt[bi][s*8]);
    }
  };

  u16* Pw = &Pb[w*16*64];
  int ntiles = 2*qt + 2;

  stage(0, 0);
  __syncthreads();

  for (int kt=0; kt<ntiles; kt++){
    int cur = kt & 1;
    if (kt+1 < ntiles) stage((kt+1)*64, cur^1);
    const u16* Kc = Kt[cur];
    const u16* Vc = Vt[cur];
    int k0 = kt*64;
    bool diag = (kt >= 2*qt);

    #pragma unroll
    for (int rg=0; rg<2; rg++){
      fx4 sacc[4];
      #pragma unroll
      for (int t=0;t<4;t++){
        int n = t*16 + ln;
        bh8 kf0 = *(const bh8*)(&Kc[(n*8 + ( quad    ^ (ln&7)))*8]);
        bh8 kf1 = *(const bh8*)(&Kc[(n*8 + ((4+quad) ^ (ln&7)))*8]);
        fx4 zz = (fx4){0.f,0.f,0.f,0.f};
        zz = __builtin_amdgcn_mfma_f32_16x16x32_bf16(qf[rg][0], kf0, zz, 0,0,0);
        zz = __builtin_amdgcn_mfma_f32_16x16x32_bf16(qf[rg][1], kf1, zz, 0,0,0);
        sacc[t] = zz;
      }

      if (diag){
        #pragma unroll
        for (int t=0;t<4;t++){
          int kg = k0 + t*16 + ln;
          #pragma unroll
          for (int r=0;r<4;r++){
            int qg = q0w + rg*16 + quad*4 + r;
            sacc[t][r] = (kg <= qg) ? sacc[t][r] : -3e38f;
          }
        }
      }

      float rowmax[4] = {-3e38f,-3e38f,-3e38f,-3e38f};
      #pragma unroll
      for (int t=0;t<4;t++)
        #pragma unroll
        for (int r=0;r<4;r++) rowmax[r] = fmaxf(rowmax[r], sacc[t][r]);
      #pragma unroll
      for (int r=0;r<4;r++)
        #pragma unroll
        for (int off=1; off<16; off<<=1)
          rowmax[r] = fmaxf(rowmax[r], __shfl_xor(rowmax[r], off, 64));

      float alpha[4], rowsum[4];
      #pragma unroll
      for (int r=0;r<4;r++){
        float mn = fmaxf(m_i[rg][r], rowmax[r]);
        alpha[r] = fexp2(m_i[rg][r] - mn);
        m_i[rg][r] = mn;
        rowsum[r] = 0.f;
      }
      #pragma unroll
      for (int t=0;t<4;t++)
        #pragma unroll
        for (int r=0;r<4;r++){
          float p = fexp2(sacc[t][r] - m_i[rg][r]);
          sacc[t][r] = p;
          rowsum[r] += p;
        }
      #pragma unroll
      for (int r=0;r<4;r++){
        #pragma unroll
        for (int off=1; off<16; off<<=1)
          rowsum[r] += __shfl_xor(rowsum[r], off, 64);
        l_i[rg][r] = l_i[rg][r]*alpha[r] + rowsum[r];
      }
      #pragma unroll
      for (int vt=0;vt<4;vt++)
        #pragma unroll
        for (int r=0;r<4;r++)
          oacc[rg][vt][r] *= alpha[r];

      #pragma unroll
      for (int t=0;t<4;t++){
        int c = 2*t + (ln>>3), jj = ln & 7;
        #pragma unroll
        for (int r=0;r<4;r++){
          int m = quad*4 + r;
          Pw[(m*8 + (c ^ (m&7)))*8 + jj] = f2bf_fast(sacc[t][r]);
        }
      }
      asm volatile("s_waitcnt lgkmcnt(0)" ::: "memory");

      __builtin_amdgcn_s_setprio(1);
      #pragma unroll
      for (int s2=0; s2<2; s2++){
        int c = s2*4 + quad;
        bh8 pf = *(const bh8*)(&Pw[(ln*8 + (c ^ (ln&7)))*8]);
        #pragma unroll
        for (int vt=0; vt<4; vt++){
          int vd = vt*16 + ln;
          bh8 vf = *(const bh8*)(&Vc[(vd*8 + (c ^ (ln&7)))*8]);
          oacc[rg][vt] = __builtin_amdgcn_mfma_f32_16x16x32_bf16(pf, vf, oacc[rg][vt], 0,0,0);
        }
      }
      __builtin_amdgcn_s_setprio(0);
      asm volatile("s_waitcnt lgkmcnt(0)" ::: "memory");
    }
    __syncthreads();
  }

  #pragma unroll
  for (int rg=0; rg<2; rg++)
    #pragma unroll
    for (int r=0;r<4;r++){
      float linv = 1.0f / l_i[rg][r];
      #pragma unroll
      for (int vt=0; vt<4; vt++){
        float ov = oacc[rg][vt][r] * linv;
        O[(size_t)(b*S_ + q0w + rg*16 + quad*4 + r)*D_ + headoff + vt*16 + ln] = f2bf(ov);
      }
    }
}

extern "C" void kernel_launch(void* const* d_in, const int* in_sizes, int n_in,
                              void* d_out, int out_size, void* d_ws, size_t ws_size,
                              hipStream_t stream){
  const float* q  = (const float*)d_in[0];
  const float* k  = (const float*)d_in[1];
  const float* v  = (const float*)d_in[2];
  const float* Wq = (const float*)d_in[3];
  const float* Wk = (const float*)d_in[4];
  const float* Wv = (const float*)d_in[5];
  const float* Wo = (const float*)d_in[6];
  // d_in[7] = causal mask, statically known -> ignored

  u16* ws  = (u16*)d_ws;
  u16* WT  = ws;                                // 4 x 1M bf16 (Wq*C1, Wk, Wv, Wo)^T
  u16* xa  = WT + (size_t)4*1024*1024;          // q bf16
  u16* xb  = xa + MD_;                          // k bf16
  u16* Qp  = xb + MD_;                          // Q proj (C1-scaled), later O
  u16* Kp  = Qp + MD_;                          // 8 MB + 4*16 MB = 72 MB ws

  // d_out (2*MD_ u16) doubles as scratch until the final GEMM:
  u16* vb  = (u16*)d_out;                       // v bf16       [0,   MD_)
  u16* VtG = vb + MD_;                          // per-head V^T [MD_, 2*MD_)

  prep_k<<<dim3(16384), 256, 0, stream>>>(q, k, v, Wq, Wk, Wv, Wo, xa, xb, vb, WT);

  gemm_qkv8<<<dim3(4,32,3), 512, 0, stream>>>(xa, vb, WT, Qp, VtG); // Qp, Kp, VtG

  attn_k<<<dim3(B_*H_, S_/128), 256, 0, stream>>>(Qp, Kp, VtG, Qp); // O over Q

  gemm_bt<1><<<dim3(8,64,1), 256, 0, stream>>>(Qp, WT + (size_t)3*1024*1024, d_out);
}

// Round 5
// 374.573 us; speedup vs baseline: 1.2176x; 1.1057x over previous
//
#include <hip/hip_runtime.h>
#include <hip/hip_bf16.h>
#include <stdint.h>

#define B_  4
#define S_  2048
#define D_  1024
#define H_  16
#define DK_ 64
#define M_  (B_*S_)                 // 8192
#define MD_ ((size_t)M_*D_)         // 8388608

typedef unsigned short u16;
typedef unsigned int   u32;
using bh8 = __attribute__((ext_vector_type(8))) short;
using fx4 = __attribute__((ext_vector_type(4))) float;
using us4 = __attribute__((ext_vector_type(4))) unsigned short;

#define C1_ 0.18033688011112042f    // (1/sqrt(64)) * log2(e)

__device__ __forceinline__ u16 f2bf(float f){
  union { float f; u32 u; } v; v.f = f;
  u32 r = v.u + 0x7FFFu + ((v.u >> 16) & 1u);
  return (u16)(r >> 16);
}
__device__ __forceinline__ u16 f2bf_fast(float f){
  union { float f; u32 u; } v; v.f = f;
  return (u16)((v.u + 0x8000u) >> 16);
}
__device__ __forceinline__ float fexp2(float x){
  float r;
  asm("v_exp_f32 %0, %1\n\ts_nop 0" : "=v"(r) : "v"(x));
  return r;
}
// async global->LDS, 16B/lane; LDS dest = wave-uniform base + lane*16
__device__ __forceinline__ void gl16(const void* g, void* l){
  __builtin_amdgcn_global_load_lds(
      (const __attribute__((address_space(1))) unsigned int*)g,
      (__attribute__((address_space(3))) unsigned int*)l, 16, 0, 0);
}

// ---------- fused prep: fp32->bf16 cvt (q,k,v) + 4x W transpose ----------
__global__ __launch_bounds__(256) void prep_k(const float* __restrict__ q,
                                              const float* __restrict__ k,
                                              const float* __restrict__ v,
                                              const float* __restrict__ W0,
                                              const float* __restrict__ W1,
                                              const float* __restrict__ W2,
                                              const float* __restrict__ W3,
                                              u16* __restrict__ dq,
                                              u16* __restrict__ dk,
                                              u16* __restrict__ dv,
                                              u16* __restrict__ WT){
  int id = blockIdx.x;
  int tid = threadIdx.x;
  if (id < 12288){
    int z = id >> 12;
    int i = (id & 4095)*256 + tid;            // n8 = 4096*256 exactly
    const float* in = (z==0)? q : (z==1)? k : v;
    u16* out = (z==0)? dq : (z==1)? dk : dv;
    const float4* p = (const float4*)(in + (size_t)i*8);
    float4 a0 = p[0], a1 = p[1];
    u16 o[8];
    o[0]=f2bf(a0.x); o[1]=f2bf(a0.y); o[2]=f2bf(a0.z); o[3]=f2bf(a0.w);
    o[4]=f2bf(a1.x); o[5]=f2bf(a1.y); o[6]=f2bf(a1.z); o[7]=f2bf(a1.w);
    *(bh8*)(out + (size_t)i*8) = *(bh8*)o;
  } else {
    int id2 = id - 12288;
    int z = id2 >> 10, b2 = id2 & 1023;
    int bx = b2 & 31, by = b2 >> 5;
    const float* in = (z==0)? W0 : (z==1)? W1 : (z==2)? W2 : W3;
    float scale = (z==0)? C1_ : 1.0f;
    u16* o = WT + (size_t)z*1024*1024;
    __shared__ u16 tile[32][33];
    int tx = tid & 31, ty = tid >> 5;         // 32 x 8
    int x0 = bx*32, y0 = by*32;
    #pragma unroll
    for (int j=0;j<32;j+=8) tile[ty+j][tx] = f2bf(in[(size_t)(y0+ty+j)*D_ + x0+tx]*scale);
    __syncthreads();
    #pragma unroll
    for (int j=0;j<32;j+=8) o[(size_t)(x0+ty+j)*D_ + y0+tx] = tile[tx][ty+j];
  }
}

// ---------- C = A @ BT^T, K=N=1024, 128x128 tile, 2-phase dbuf ----------
// MODE 1: fp32 C (final O @ Wo).
template<int MODE>
__global__ __launch_bounds__(256) void gemm_bt(const u16* __restrict__ Abase,
                                               const u16* __restrict__ BTbase,
                                               void* __restrict__ Cbase){
  __shared__ __align__(16) u16 Asl[2][128*64];
  __shared__ __align__(16) u16 Bsl[2][128*64];
  int z = blockIdx.z;
  const u16* A  = Abase  + (size_t)z*MD_;
  const u16* BT = BTbase + (size_t)z*1024*1024;
  int tid  = threadIdx.x;
  int w    = tid >> 6, lane = tid & 63, quad = lane >> 4, ln = lane & 15;
  int waveM = w >> 1, waveN = w & 1;
  int rowBase = blockIdx.y*128, colBase = blockIdx.x*128;

  fx4 acc[4][4];
  #pragma unroll
  for (int i=0;i<4;i++)
    #pragma unroll
    for (int j=0;j<4;j++) acc[i][j] = (fx4){0.f,0.f,0.f,0.f};

  auto stage = [&](int k0, int bi){
    #pragma unroll
    for (int i=0;i<4;i++){
      int slot = i*256 + tid;
      int kc = slot >> 7, r = slot & 127;
      gl16(&A [(size_t)(rowBase + r)*D_ + k0 + kc*8], &Asl[bi][slot*8]);
      gl16(&BT[(size_t)(colBase + r)*D_ + k0 + kc*8], &Bsl[bi][slot*8]);
    }
  };

  stage(0, 0);
  __syncthreads();

  for (int t = 0; t < 16; ++t){
    int cur = t & 1;
    if (t+1 < 16) stage((t+1)*64, cur^1);
    #pragma unroll
    for (int ks=0; ks<2; ks++){
      bh8 af[4], bf[4];
      #pragma unroll
      for (int tt=0;tt<4;tt++){
        af[tt] = *(const bh8*)(&Asl[cur][((ks*4+quad)*128 + waveM*64 + tt*16 + ln)*8]);
        bf[tt] = *(const bh8*)(&Bsl[cur][((ks*4+quad)*128 + waveN*64 + tt*16 + ln)*8]);
      }
      #pragma unroll
      for (int i=0;i<4;i++)
        #pragma unroll
        for (int j=0;j<4;j++)
          acc[i][j] = __builtin_amdgcn_mfma_f32_16x16x32_bf16(af[i], bf[j], acc[i][j], 0, 0, 0);
    }
    __syncthreads();
  }

  #pragma unroll
  for (int i=0;i<4;i++){
    int row0 = rowBase + waveM*64 + i*16 + quad*4;
    #pragma unroll
    for (int j=0;j<4;j++){
      int col = colBase + waveN*64 + j*16 + ln;
      #pragma unroll
      for (int r=0;r<4;r++){
        if (MODE == 1) ((float*)Cbase)[(size_t)(row0 + r)*D_ + col] = acc[i][j][r];
        else ((u16*)Cbase + (size_t)z*MD_)[(size_t)(row0 + r)*D_ + col] = f2bf(acc[i][j][r]);
      }
    }
  }
}

// ---------- fused Q/K/V projection: 256x256 tile, BK=64, 8-phase ----------
// (R4-verified, unchanged)
__global__ __launch_bounds__(512, 2) void gemm_qkv8(const u16* __restrict__ Aqk,
                                                    const u16* __restrict__ Av,
                                                    const u16* __restrict__ WTb,
                                                    u16* __restrict__ Cqk,
                                                    u16* __restrict__ VtOut){
  __shared__ __align__(16) u16 AL[2][2][8192];   // 64 KB
  __shared__ __align__(16) u16 BL[2][2][8192];   // 64 KB
  int z = blockIdx.z;
  const u16* A  = (z < 2) ? (Aqk + (size_t)z*MD_) : Av;
  const u16* BT = WTb + (size_t)z*1024*1024;
  int tid = threadIdx.x;
  int w = tid >> 6, lane = tid & 63, quad = lane >> 4, ln = lane & 15;
  int wm = w >> 2, wn = w & 3;
  int rowBase = blockIdx.y*256, colBase = blockIdx.x*256;

  auto stageHT = [&](int mat, int kt, int hf){
    int buf = kt & 1;
    u16* dst = mat ? &BL[buf][hf][0] : &AL[buf][hf][0];
    const u16* src = mat ? BT : A;
    int gbase = (mat ? colBase : rowBase) + hf*128;
    int k0 = kt*64;
    #pragma unroll
    for (int j=0;j<2;j++){
      int slot = j*512 + tid;
      int kc = slot >> 7, r = slot & 127;
      gl16(&src[(size_t)(gbase + r)*D_ + k0 + kc*8], dst + slot*8);
    }
  };

  fx4 acc[8][4];
  #pragma unroll
  for (int i=0;i<8;i++)
    #pragma unroll
    for (int j=0;j<4;j++) acc[i][j] = (fx4){0.f,0.f,0.f,0.f};

  stageHT(0,0,0); stageHT(0,0,1);
  stageHT(1,0,0); stageHT(1,0,1);
  stageHT(1,1,0); stageHT(1,1,1);
  asm volatile("s_waitcnt vmcnt(4)" ::: "memory");
  __builtin_amdgcn_s_barrier();

  bh8 bfr[4][2];
  for (int it = 0; it < 8; ++it){
    int t = 2*it;
    #pragma unroll
    for (int p = 0; p < 8; ++p){
      const int buf = p >> 2;
      const int q = p & 3;
      const u16* Ah = &AL[buf][wm][0];
      const u16* Bh = &BL[buf][wn>>1][0];

      if (q == 0){
        #pragma unroll
        for (int n=0;n<4;n++)
          #pragma unroll
          for (int ks=0;ks<2;ks++)
            bfr[n][ks] = *(const bh8*)(&Bh[((ks*4+quad)*128 + (wn&1)*64 + n*16 + ln)*8]);
      }
      bh8 af[2][2];
      #pragma unroll
      for (int mi=0;mi<2;mi++)
        #pragma unroll
        for (int ks=0;ks<2;ks++)
          af[mi][ks] = *(const bh8*)(&Ah[((ks*4+quad)*128 + (q*2+mi)*16 + ln)*8]);

      switch(p){
        case 0: stageHT(0, t+1, 0); break;
        case 1: stageHT(0, t+1, 1); break;
        case 2: if (t+2 < 16) stageHT(1, t+2, 0); break;
        case 3: if (t+2 < 16) stageHT(1, t+2, 1); break;
        case 4: if (t+2 < 16) stageHT(0, t+2, 0); break;
        case 5: if (t+2 < 16) stageHT(0, t+2, 1); break;
        case 6: if (t+3 < 16) stageHT(1, t+3, 0); break;
        case 7: if (t+3 < 16) stageHT(1, t+3, 1); break;
      }

      if (p == 3){
        if (t+2 < 16) asm volatile("s_waitcnt vmcnt(4)" ::: "memory");
        else          asm volatile("s_waitcnt vmcnt(0)" ::: "memory");
      }
      if (p == 7 && t+2 < 16) asm volatile("s_waitcnt vmcnt(4)" ::: "memory");

      __builtin_amdgcn_s_barrier();
      asm volatile("s_waitcnt lgkmcnt(0)" ::: "memory");

      __builtin_amdgcn_s_setprio(1);
      #pragma unroll
      for (int mi=0;mi<2;mi++)
        #pragma unroll
        for (int n=0;n<4;n++)
          #pragma unroll
          for (int ks=0;ks<2;ks++)
            acc[q*2+mi][n] = __builtin_amdgcn_mfma_f32_16x16x32_bf16(
                                af[mi][ks], bfr[n][ks], acc[q*2+mi][n], 0,0,0);
      __builtin_amdgcn_s_setprio(0);
      __builtin_amdgcn_s_barrier();
    }
  }

  #pragma unroll
  for (int m=0;m<8;m++){
    int row0 = rowBase + wm*128 + m*16 + quad*4;
    #pragma unroll
    for (int n=0;n<4;n++){
      int col = colBase + wn*64 + n*16 + ln;
      if (z == 2){
        int bb = row0 >> 11, tok = row0 & (S_-1);
        int hh = col >> 6,  vd  = col & 63;
        us4 pk;
        #pragma unroll
        for (int r=0;r<4;r++) pk[r] = f2bf(acc[m][n][r]);
        *(us4*)&VtOut[((size_t)((bb*16+hh)*64+vd))*S_ + tok] = pk;
      } else {
        #pragma unroll
        for (int r=0;r<4;r++)
          (Cqk + (size_t)z*MD_)[(size_t)(row0 + r)*D_ + col] = f2bf(acc[m][n][r]);
      }
    }
  }
}

// ---------- flash attention, causal ----------
// SWAPPED QK^T (T12-style): sacc = mfma(K, Q) -> S^T with query = ln
// (lane-local column), keys = quad*4+r (in-register rows). Softmax row
// reduce = in-register tree + 2 shfl_xor (16,32) instead of 16 shfl; m/l
// are one scalar per lane; P-transpose write = 4x ds_write_b64 (keys
// contiguous in-lane) instead of 16x ds_write_b16. alpha / 1/l are moved
// to oacc rows (q = quad*4+r) via 4 bpermute broadcasts per rg.
// Everything else (staging, dbuf, one barrier/tile, swizzle) unchanged.
__global__ __launch_bounds__(256) void attn_k(const u16* __restrict__ Q,
                                              const u16* __restrict__ Kp,
                                              const u16* __restrict__ VtG,
                                              u16* __restrict__ O){
  __shared__ __align__(16) u16 Kt[2][64*64];    // 2 x 8 KB
  __shared__ __align__(16) u16 Vt[2][64*64];    // 2 x 8 KB
  __shared__ __align__(16) u16 Pb[4*16*64];     // 8 KB

  int bh = blockIdx.x; int b = bh>>4, h = bh&15;
  int qt = (int)gridDim.y - 1 - (int)blockIdx.y;   // heavy dispatch-waves first
  int tid = threadIdx.x;
  int w = tid >> 6, lane = tid & 63, quad = lane >> 4, ln = lane & 15;
  int q0w = qt*128 + w*32;
  size_t headoff = (size_t)h*DK_;

  bh8 qf[2][2];
  #pragma unroll
  for (int rg=0; rg<2; rg++){
    const u16* qp = Q + (size_t)(b*S_ + q0w + rg*16 + ln)*D_ + headoff + quad*8;
    qf[rg][0] = *(const bh8*)qp;
    qf[rg][1] = *(const bh8*)(qp + 32);
  }

  float m_i[2], l_i[2];
  fx4 oacc[2][4];
  #pragma unroll
  for (int rg=0; rg<2; rg++){
    m_i[rg] = -3e38f; l_i[rg] = 0.f;
    #pragma unroll
    for (int r=0;r<4;r++) oacc[rg][r] = (fx4){0.f,0.f,0.f,0.f};
  }

  auto stage = [&](int k0, int bi){
    #pragma unroll
    for (int i=0;i<2;i++){
      int s = i*256 + tid;
      int n = s >> 3, kc = (s & 7) ^ (n & 7);
      gl16(&Kp[(size_t)(b*S_ + k0 + n)*D_ + headoff + kc*8], &Kt[bi][s*8]);
    }
    #pragma unroll
    for (int i=0;i<2;i++){
      int s = i*256 + tid;
      int vd = s >> 3, c = (s & 7) ^ (vd & 7);
      gl16(&VtG[(size_t)(bh*64 + vd)*S_ + k0 + c*8], &Vt[bi][s*8]);
    }
  };

  u16* Pw = &Pb[w*16*64];
  int ntiles = 2*qt + 2;           // k-tiles of 64 covering [0, (qt+1)*128)

  stage(0, 0);
  __syncthreads();                 // drain prologue staging

  for (int kt=0; kt<ntiles; kt++){
    int cur = kt & 1;
    if (kt+1 < ntiles) stage((kt+1)*64, cur^1);   // prefetch, no wait
    const u16* Kc = Kt[cur];
    const u16* Vc = Vt[cur];
    int k0 = kt*64;
    bool diag = (kt >= 2*qt);      // last two tiles straddle the diagonal

    #pragma unroll
    for (int rg=0; rg<2; rg++){
      // QK^T swapped: sacc[t] = K_frag[t] x Q_frag -> S^T
      // lane (quad,ln): keys k0 + t*16 + quad*4 + r, query q0w + rg*16 + ln
      fx4 sacc[4];
      #pragma unroll
      for (int t=0;t<4;t++){
        int n = t*16 + ln;
        bh8 kf0 = *(const bh8*)(&Kc[(n*8 + ( quad    ^ (ln&7)))*8]);
        bh8 kf1 = *(const bh8*)(&Kc[(n*8 + ((4+quad) ^ (ln&7)))*8]);
        fx4 zz = (fx4){0.f,0.f,0.f,0.f};
        zz = __builtin_amdgcn_mfma_f32_16x16x32_bf16(kf0, qf[rg][0], zz, 0,0,0);
        zz = __builtin_amdgcn_mfma_f32_16x16x32_bf16(kf1, qf[rg][1], zz, 0,0,0);
        sacc[t] = zz;
      }

      int qg = q0w + rg*16 + ln;
      if (diag){
        #pragma unroll
        for (int t=0;t<4;t++){
          #pragma unroll
          for (int r=0;r<4;r++){
            int kg = k0 + t*16 + quad*4 + r;
            sacc[t][r] = (kg <= qg) ? sacc[t][r] : -3e38f;
          }
        }
      }

      // row reduce: in-register tree + 2 shfl (quad groups share query ln)
      float tm[4];
      #pragma unroll
      for (int t=0;t<4;t++)
        tm[t] = fmaxf(fmaxf(sacc[t][0], sacc[t][1]), fmaxf(sacc[t][2], sacc[t][3]));
      float mloc = fmaxf(fmaxf(tm[0], tm[1]), fmaxf(tm[2], tm[3]));
      mloc = fmaxf(mloc, __shfl_xor(mloc, 16, 64));
      mloc = fmaxf(mloc, __shfl_xor(mloc, 32, 64));

      float mn = fmaxf(m_i[rg], mloc);
      float alpha = fexp2(m_i[rg] - mn);
      m_i[rg] = mn;

      float ts[4];
      #pragma unroll
      for (int t=0;t<4;t++){
        #pragma unroll
        for (int r=0;r<4;r++) sacc[t][r] = fexp2(sacc[t][r] - mn);
        ts[t] = (sacc[t][0] + sacc[t][1]) + (sacc[t][2] + sacc[t][3]);
      }
      float rs = (ts[0] + ts[1]) + (ts[2] + ts[3]);
      rs += __shfl_xor(rs, 16, 64);
      rs += __shfl_xor(rs, 32, 64);
      l_i[rg] = l_i[rg]*alpha + rs;

      // broadcast alpha from query=ln lanes to oacc rows q=quad*4+r
      float al[4];
      #pragma unroll
      for (int r=0;r<4;r++) al[r] = __shfl(alpha, quad*4 + r, 64);
      #pragma unroll
      for (int vt=0;vt<4;vt++)
        #pragma unroll
        for (int r=0;r<4;r++)
          oacc[rg][vt][r] *= al[r];

      // P^T -> P: lane holds keys t*16+quad*4+{0..3} of query row ln,
      // contiguous -> one b64 write per t into swizzled chunk slots
      #pragma unroll
      for (int t=0;t<4;t++){
        int c = 2*t + (quad>>1);
        us4 pk;
        #pragma unroll
        for (int r=0;r<4;r++) pk[r] = f2bf_fast(sacc[t][r]);
        *(us4*)&Pw[(ln*8 + (c ^ (ln&7)))*8 + (quad&1)*4] = pk;
      }
      asm volatile("s_waitcnt lgkmcnt(0)" ::: "memory");

      // PV: 64 keys in 2 chunks, vdim in 4 subtiles (unchanged)
      __builtin_amdgcn_s_setprio(1);
      #pragma unroll
      for (int s2=0; s2<2; s2++){
        int c = s2*4 + quad;
        bh8 pf = *(const bh8*)(&Pw[(ln*8 + (c ^ (ln&7)))*8]);
        #pragma unroll
        for (int vt=0; vt<4; vt++){
          int vd = vt*16 + ln;
          bh8 vf = *(const bh8*)(&Vc[(vd*8 + (c ^ (ln&7)))*8]);
          oacc[rg][vt] = __builtin_amdgcn_mfma_f32_16x16x32_bf16(pf, vf, oacc[rg][vt], 0,0,0);
        }
      }
      __builtin_amdgcn_s_setprio(0);
      asm volatile("s_waitcnt lgkmcnt(0)" ::: "memory");  // drain before Pw reuse
    }
    __syncthreads();   // prefetch arrived (vmcnt drain overlapped compute); buffers safe
  }

  // epilogue: O = acc / l ; 1/l broadcast to oacc rows q=quad*4+r
  #pragma unroll
  for (int rg=0; rg<2; rg++){
    float linv = 1.0f / l_i[rg];
    float lb[4];
    #pragma unroll
    for (int r=0;r<4;r++) lb[r] = __shfl(linv, quad*4 + r, 64);
    #pragma unroll
    for (int r=0;r<4;r++){
      #pragma unroll
      for (int vt=0; vt<4; vt++){
        float ov = oacc[rg][vt][r] * lb[r];
        O[(size_t)(b*S_ + q0w + rg*16 + quad*4 + r)*D_ + headoff + vt*16 + ln] = f2bf(ov);
      }
    }
  }
}

extern "C" void kernel_launch(void* const* d_in, const int* in_sizes, int n_in,
                              void* d_out, int out_size, void* d_ws, size_t ws_size,
                              hipStream_t stream){
  const float* q  = (const float*)d_in[0];
  const float* k  = (const float*)d_in[1];
  const float* v  = (const float*)d_in[2];
  const float* Wq = (const float*)d_in[3];
  const float* Wk = (const float*)d_in[4];
  const float* Wv = (const float*)d_in[5];
  const float* Wo = (const float*)d_in[6];
  // d_in[7] = causal mask, statically known -> ignored

  u16* ws  = (u16*)d_ws;
  u16* WT  = ws;                                // 4 x 1M bf16 (Wq*C1, Wk, Wv, Wo)^T
  u16* xa  = WT + (size_t)4*1024*1024;          // q bf16
  u16* xb  = xa + MD_;                          // k bf16
  u16* Qp  = xb + MD_;                          // Q proj (C1-scaled), later O
  u16* Kp  = Qp + MD_;                          // 8 MB + 4*16 MB = 72 MB ws

  // d_out (2*MD_ u16) doubles as scratch until the final GEMM:
  u16* vb  = (u16*)d_out;                       // v bf16       [0,   MD_)
  u16* VtG = vb + MD_;                          // per-head V^T [MD_, 2*MD_)

  prep_k<<<dim3(16384), 256, 0, stream>>>(q, k, v, Wq, Wk, Wv, Wo, xa, xb, vb, WT);

  gemm_qkv8<<<dim3(4,32,3), 512, 0, stream>>>(xa, vb, WT, Qp, VtG); // Qp, Kp, VtG

  attn_k<<<dim3(B_*H_, S_/128), 256, 0, stream>>>(Qp, Kp, VtG, Qp); // O over Q

  gemm_bt<1><<<dim3(8,64,1), 256, 0, stream>>>(Qp, WT + (size_t)3*1024*1024, d_out);
}

// Round 6
// 327.013 us; speedup vs baseline: 1.3946x; 1.1454x over previous
//
#include <hip/hip_runtime.h>
#include <hip/hip_bf16.h>
#include <stdint.h>

#define B_  4
#define S_  2048
#define D_  1024
#define H_  16
#define DK_ 64
#define M_  (B_*S_)                 // 8192
#define MD_ ((size_t)M_*D_)         // 8388608

typedef unsigned short u16;
typedef unsigned int   u32;
using bh8 = __attribute__((ext_vector_type(8))) short;
using fx4 = __attribute__((ext_vector_type(4))) float;
using us4 = __attribute__((ext_vector_type(4))) unsigned short;

#define C1_ 0.18033688011112042f    // (1/sqrt(64)) * log2(e)

__device__ __forceinline__ u16 f2bf(float f){
  union { float f; u32 u; } v; v.f = f;
  u32 r = v.u + 0x7FFFu + ((v.u >> 16) & 1u);
  return (u16)(r >> 16);
}
__device__ __forceinline__ u16 f2bf_fast(float f){
  union { float f; u32 u; } v; v.f = f;
  return (u16)((v.u + 0x8000u) >> 16);
}
__device__ __forceinline__ float fexp2(float x){
  float r;
  asm("v_exp_f32 %0, %1\n\ts_nop 0" : "=v"(r) : "v"(x));
  return r;
}
// async global->LDS, 16B/lane; LDS dest = wave-uniform base + lane*16
__device__ __forceinline__ void gl16(const void* g, void* l){
  __builtin_amdgcn_global_load_lds(
      (const __attribute__((address_space(1))) unsigned int*)g,
      (__attribute__((address_space(3))) unsigned int*)l, 16, 0, 0);
}

// ---------- fused prep: fp32->bf16 cvt (q,k,v) + 4x W transpose ----------
__global__ __launch_bounds__(256) void prep_k(const float* __restrict__ q,
                                              const float* __restrict__ k,
                                              const float* __restrict__ v,
                                              const float* __restrict__ W0,
                                              const float* __restrict__ W1,
                                              const float* __restrict__ W2,
                                              const float* __restrict__ W3,
                                              u16* __restrict__ dq,
                                              u16* __restrict__ dk,
                                              u16* __restrict__ dv,
                                              u16* __restrict__ WT){
  int id = blockIdx.x;
  int tid = threadIdx.x;
  if (id < 12288){
    int z = id >> 12;
    int i = (id & 4095)*256 + tid;            // n8 = 4096*256 exactly
    const float* in = (z==0)? q : (z==1)? k : v;
    u16* out = (z==0)? dq : (z==1)? dk : dv;
    const float4* p = (const float4*)(in + (size_t)i*8);
    float4 a0 = p[0], a1 = p[1];
    u16 o[8];
    o[0]=f2bf(a0.x); o[1]=f2bf(a0.y); o[2]=f2bf(a0.z); o[3]=f2bf(a0.w);
    o[4]=f2bf(a1.x); o[5]=f2bf(a1.y); o[6]=f2bf(a1.z); o[7]=f2bf(a1.w);
    *(bh8*)(out + (size_t)i*8) = *(bh8*)o;
  } else {
    int id2 = id - 12288;
    int z = id2 >> 10, b2 = id2 & 1023;
    int bx = b2 & 31, by = b2 >> 5;
    const float* in = (z==0)? W0 : (z==1)? W1 : (z==2)? W2 : W3;
    float scale = (z==0)? C1_ : 1.0f;
    u16* o = WT + (size_t)z*1024*1024;
    __shared__ u16 tile[32][33];
    int tx = tid & 31, ty = tid >> 5;         // 32 x 8
    int x0 = bx*32, y0 = by*32;
    #pragma unroll
    for (int j=0;j<32;j+=8) tile[ty+j][tx] = f2bf(in[(size_t)(y0+ty+j)*D_ + x0+tx]*scale);
    __syncthreads();
    #pragma unroll
    for (int j=0;j<32;j+=8) o[(size_t)(x0+ty+j)*D_ + y0+tx] = tile[tx][ty+j];
  }
}

// ---------- unified 8-wave GEMM: 128(M) x 256(N) tile, BK=64 ----------
// C = A @ BT^T, K = 1024. MODE 0: QKV projection (768 blocks = 3 exact
// rounds; z in {0:Q,1:K,2:V->VtOut}); MODE 1: fp32 C (O @ Wo, 256 blocks
// = 1 exact round). Replaces the 256^2 kernel whose 384-block grid ran
// 1.5 rounds (33% tail idle) and the 128^2 2-phase final GEMM (~370 TF).
//
// 8 waves = 2M x 4N, per-wave out 64x64 (acc[4][4]). LDS 96 KB:
// A[2][128*64], B[2][256*64], ROW-major with XOR swizzle
// (u16 idx = row*64 + (kc^(row&7))*8): staging is fully coalesced (8
// lanes = one 128B line, kills the old 16B/lane row-strided L2 sector
// waste) and ds_reads stay <=2-way bank aliased (free, m136). Swizzle
// applied on BOTH global source and ds_read (both-sides rule).
//
// 4 phases per 2-tile iter, 2 barriers/phase. Region-liveness staging:
//   ph0 (t,q0):  read B(t)8 + afA 4 + afB 4 ; stage B(t+1)#3, A(t+1)#0,1
//   ph1 (t,q1):  stage B(t+2)#0,1,2 ; GATE vmcnt(3)  [t+1 resident]
//   ph2 (t+1,q0): reads ; stage B(t+2)#3, A(t+2)#0,1
//   ph3 (t+1,q1): stage B(t+3)#0,1,2 ; GATE vmcnt(3) [t+2 resident]
// B region last read at q0, A drained by q1's lgkmcnt(0) -> every
// restage is >=1 barrier after its region's last read. FIFO-checked:
// gates retire exactly the 6 scalls of the tile needed next.
template<int MODE>
__global__ __launch_bounds__(512) void gemm8(const u16* __restrict__ Aqk,
                                             const u16* __restrict__ Av,
                                             const u16* __restrict__ WTb,
                                             u16* __restrict__ Cqk,
                                             u16* __restrict__ VtOut,
                                             float* __restrict__ Cf){
  __shared__ __align__(16) u16 AL[2][128*64];   // 2 x 16 KB
  __shared__ __align__(16) u16 BL[2][256*64];   // 2 x 32 KB

  // XCD-co-located tile map: the 4 col-blocks of an A row-panel share an
  // XCD L2 (hw round-robins blockIdx%8 -> XCD). Bijective by construction.
  int hbid = blockIdx.x;
  int xcd = hbid & 7, slot = hbid >> 3;
  int pg  = xcd * (MODE==0 ? 24 : 8) + (slot >> 2);
  int x   = slot & 3;
  int y   = (MODE==0) ? (pg & 63) : pg;
  int z   = (MODE==0) ? (pg >> 6) : 0;

  const u16* A  = (MODE==0 && z==2) ? Av : (Aqk + (size_t)z*MD_);
  const u16* BT = WTb + (size_t)z*1024*1024;
  int tid = threadIdx.x;
  int w = tid >> 6, lane = tid & 63, quad = lane >> 4, ln = lane & 15;
  int wm = w >> 2, wn = w & 3;
  int rowBase = y*128, colBase = x*256;

  // staging scall: 512 thr x 16B; coalesced rows, pre-swizzled source
  auto sA = [&](int buf, int kt, int c){      // c in {0,1}
    int s = c*512 + tid;
    int row = s >> 3, kc = (s & 7) ^ (row & 7);
    gl16(&A[(size_t)(rowBase + row)*D_ + kt*64 + kc*8], &AL[buf][s*8]);
  };
  auto sB = [&](int buf, int kt, int c){      // c in {0..3}
    int s = c*512 + tid;
    int row = s >> 3, kc = (s & 7) ^ (row & 7);
    gl16(&BT[(size_t)(colBase + row)*D_ + kt*64 + kc*8], &BL[buf][s*8]);
  };
  // swizzled ds_read index (u16)
  auto ridx = [&](int row, int kc){ return row*64 + ((kc ^ (row & 7))*8); };

  fx4 acc[4][4];
  #pragma unroll
  for (int i=0;i<4;i++)
    #pragma unroll
    for (int j=0;j<4;j++) acc[i][j] = (fx4){0.f,0.f,0.f,0.f};

  // prologue: tile0 full (6 scalls) + B(1)#0,1,2 -> gate leaves B(1)'s 3
  sA(0,0,0); sA(0,0,1); sB(0,0,0); sB(0,0,1); sB(0,0,2); sB(0,0,3);
  sB(1,1,0); sB(1,1,1); sB(1,1,2);
  asm volatile("s_waitcnt vmcnt(3)" ::: "memory");
  __builtin_amdgcn_s_barrier();

  for (int it = 0; it < 8; ++it){
    int t = 2*it;
    bool h2 = (t+2 < 16), h3 = (t+3 < 16);
    #pragma unroll
    for (int half = 0; half < 2; ++half){     // buf == half (t even)
      const u16* Ab = &AL[half][0];
      const u16* Bb = &BL[half][0];

      // ---- q0 phase ----
      bh8 bfr[4][2], af0[2][2], af1[2][2];
      #pragma unroll
      for (int n=0;n<4;n++)
        #pragma unroll
        for (int ks=0;ks<2;ks++)
          bfr[n][ks] = *(const bh8*)(&Bb[ridx(wn*64 + n*16 + ln, ks*4+quad)]);
      #pragma unroll
      for (int mi=0;mi<2;mi++)
        #pragma unroll
        for (int ks=0;ks<2;ks++)
          af0[mi][ks] = *(const bh8*)(&Ab[ridx(wm*64 + mi*16 + ln, ks*4+quad)]);
      #pragma unroll
      for (int mi=0;mi<2;mi++)
        #pragma unroll
        for (int ks=0;ks<2;ks++)
          af1[mi][ks] = *(const bh8*)(&Ab[ridx(wm*64 + 32 + mi*16 + ln, ks*4+quad)]);

      if (half == 0){                         // stage B(t+1)#3, A(t+1)#0,1
        sB(1, t+1, 3); sA(1, t+1, 0); sA(1, t+1, 1);
      } else if (h2){                         // stage B(t+2)#3, A(t+2)#0,1
        sB(0, t+2, 3); sA(0, t+2, 0); sA(0, t+2, 1);
      }
      __builtin_amdgcn_s_barrier();
      asm volatile("s_waitcnt lgkmcnt(4)" ::: "memory");   // bfr+af0 done
      __builtin_amdgcn_s_setprio(1);
      #pragma unroll
      for (int mi=0;mi<2;mi++)
        #pragma unroll
        for (int n=0;n<4;n++)
          #pragma unroll
          for (int ks=0;ks<2;ks++)
            acc[mi][n] = __builtin_amdgcn_mfma_f32_16x16x32_bf16(
                            af0[mi][ks], bfr[n][ks], acc[mi][n], 0,0,0);
      __builtin_amdgcn_s_setprio(0);
      __builtin_amdgcn_s_barrier();

      // ---- q1 phase ----
      if (half == 0){
        if (h2){ sB(0, t+2, 0); sB(0, t+2, 1); sB(0, t+2, 2); }
        if (h2) asm volatile("s_waitcnt vmcnt(3)" ::: "memory");  // t+1 resident
        else    asm volatile("s_waitcnt vmcnt(0)" ::: "memory");
      } else {
        if (h3){ sB(1, t+3, 0); sB(1, t+3, 1); sB(1, t+3, 2); }
        if (h3) asm volatile("s_waitcnt vmcnt(3)" ::: "memory");  // t+2 resident
        else    asm volatile("s_waitcnt vmcnt(0)" ::: "memory");
      }
      __builtin_amdgcn_s_barrier();
      asm volatile("s_waitcnt lgkmcnt(0)" ::: "memory");   // af1 done
      __builtin_amdgcn_s_setprio(1);
      #pragma unroll
      for (int mi=0;mi<2;mi++)
        #pragma unroll
        for (int n=0;n<4;n++)
          #pragma unroll
          for (int ks=0;ks<2;ks++)
            acc[2+mi][n] = __builtin_amdgcn_mfma_f32_16x16x32_bf16(
                              af1[mi][ks], bfr[n][ks], acc[2+mi][n], 0,0,0);
      __builtin_amdgcn_s_setprio(0);
      __builtin_amdgcn_s_barrier();
    }
  }

  // epilogue: C/D layout col = lane&15, row = quad*4 + reg
  #pragma unroll
  for (int m=0;m<4;m++){
    int row0 = rowBase + wm*64 + m*16 + quad*4;
    #pragma unroll
    for (int n=0;n<4;n++){
      int col = colBase + wn*64 + n*16 + ln;
      if (MODE == 1){
        #pragma unroll
        for (int r=0;r<4;r++)
          Cf[(size_t)(row0 + r)*D_ + col] = acc[m][n][r];
      } else if (z == 2){
        // per-head V^T: VtOut[(b*16+h)*64+vd][token]
        int bb = row0 >> 11, tok = row0 & (S_-1);
        int hh = col >> 6,  vd  = col & 63;
        us4 pk;
        #pragma unroll
        for (int r=0;r<4;r++) pk[r] = f2bf(acc[m][n][r]);
        *(us4*)&VtOut[((size_t)((bb*16+hh)*64+vd))*S_ + tok] = pk;
      } else {
        #pragma unroll
        for (int r=0;r<4;r++)
          (Cqk + (size_t)z*MD_)[(size_t)(row0 + r)*D_ + col] = f2bf(acc[m][n][r]);
      }
    }
  }
}

// ---------- flash attention, causal (R5-verified, unchanged) ----------
// Swapped QK^T: sacc = mfma(K, Q) -> S^T, query = ln lane-local; softmax
// reduce = reg tree + 2 shfl_xor; P write = b64 of key-quads; alpha/1/l
// broadcast to oacc rows via shfl.
__global__ __launch_bounds__(256) void attn_k(const u16* __restrict__ Q,
                                              const u16* __restrict__ Kp,
                                              const u16* __restrict__ VtG,
                                              u16* __restrict__ O){
  __shared__ __align__(16) u16 Kt[2][64*64];    // 2 x 8 KB
  __shared__ __align__(16) u16 Vt[2][64*64];    // 2 x 8 KB
  __shared__ __align__(16) u16 Pb[4*16*64];     // 8 KB

  int bh = blockIdx.x; int b = bh>>4, h = bh&15;
  int qt = (int)gridDim.y - 1 - (int)blockIdx.y;   // heavy dispatch-waves first
  int tid = threadIdx.x;
  int w = tid >> 6, lane = tid & 63, quad = lane >> 4, ln = lane & 15;
  int q0w = qt*128 + w*32;
  size_t headoff = (size_t)h*DK_;

  bh8 qf[2][2];
  #pragma unroll
  for (int rg=0; rg<2; rg++){
    const u16* qp = Q + (size_t)(b*S_ + q0w + rg*16 + ln)*D_ + headoff + quad*8;
    qf[rg][0] = *(const bh8*)qp;
    qf[rg][1] = *(const bh8*)(qp + 32);
  }

  float m_i[2], l_i[2];
  fx4 oacc[2][4];
  #pragma unroll
  for (int rg=0; rg<2; rg++){
    m_i[rg] = -3e38f; l_i[rg] = 0.f;
    #pragma unroll
    for (int r=0;r<4;r++) oacc[rg][r] = (fx4){0.f,0.f,0.f,0.f};
  }

  auto stage = [&](int k0, int bi){
    #pragma unroll
    for (int i=0;i<2;i++){
      int s = i*256 + tid;
      int n = s >> 3, kc = (s & 7) ^ (n & 7);
      gl16(&Kp[(size_t)(b*S_ + k0 + n)*D_ + headoff + kc*8], &Kt[bi][s*8]);
    }
    #pragma unroll
    for (int i=0;i<2;i++){
      int s = i*256 + tid;
      int vd = s >> 3, c = (s & 7) ^ (vd & 7);
      gl16(&VtG[(size_t)(bh*64 + vd)*S_ + k0 + c*8], &Vt[bi][s*8]);
    }
  };

  u16* Pw = &Pb[w*16*64];
  int ntiles = 2*qt + 2;           // k-tiles of 64 covering [0, (qt+1)*128)

  stage(0, 0);
  __syncthreads();                 // drain prologue staging

  for (int kt=0; kt<ntiles; kt++){
    int cur = kt & 1;
    if (kt+1 < ntiles) stage((kt+1)*64, cur^1);   // prefetch, no wait
    const u16* Kc = Kt[cur];
    const u16* Vc = Vt[cur];
    int k0 = kt*64;
    bool diag = (kt >= 2*qt);      // last two tiles straddle the diagonal

    #pragma unroll
    for (int rg=0; rg<2; rg++){
      fx4 sacc[4];
      #pragma unroll
      for (int t=0;t<4;t++){
        int n = t*16 + ln;
        bh8 kf0 = *(const bh8*)(&Kc[(n*8 + ( quad    ^ (ln&7)))*8]);
        bh8 kf1 = *(const bh8*)(&Kc[(n*8 + ((4+quad) ^ (ln&7)))*8]);
        fx4 zz = (fx4){0.f,0.f,0.f,0.f};
        zz = __builtin_amdgcn_mfma_f32_16x16x32_bf16(kf0, qf[rg][0], zz, 0,0,0);
        zz = __builtin_amdgcn_mfma_f32_16x16x32_bf16(kf1, qf[rg][1], zz, 0,0,0);
        sacc[t] = zz;
      }

      int qg = q0w + rg*16 + ln;
      if (diag){
        #pragma unroll
        for (int t=0;t<4;t++){
          #pragma unroll
          for (int r=0;r<4;r++){
            int kg = k0 + t*16 + quad*4 + r;
            sacc[t][r] = (kg <= qg) ? sacc[t][r] : -3e38f;
          }
        }
      }

      float tm[4];
      #pragma unroll
      for (int t=0;t<4;t++)
        tm[t] = fmaxf(fmaxf(sacc[t][0], sacc[t][1]), fmaxf(sacc[t][2], sacc[t][3]));
      float mloc = fmaxf(fmaxf(tm[0], tm[1]), fmaxf(tm[2], tm[3]));
      mloc = fmaxf(mloc, __shfl_xor(mloc, 16, 64));
      mloc = fmaxf(mloc, __shfl_xor(mloc, 32, 64));

      float mn = fmaxf(m_i[rg], mloc);
      float alpha = fexp2(m_i[rg] - mn);
      m_i[rg] = mn;

      float ts[4];
      #pragma unroll
      for (int t=0;t<4;t++){
        #pragma unroll
        for (int r=0;r<4;r++) sacc[t][r] = fexp2(sacc[t][r] - mn);
        ts[t] = (sacc[t][0] + sacc[t][1]) + (sacc[t][2] + sacc[t][3]);
      }
      float rs = (ts[0] + ts[1]) + (ts[2] + ts[3]);
      rs += __shfl_xor(rs, 16, 64);
      rs += __shfl_xor(rs, 32, 64);
      l_i[rg] = l_i[rg]*alpha + rs;

      float al[4];
      #pragma unroll
      for (int r=0;r<4;r++) al[r] = __shfl(alpha, quad*4 + r, 64);
      #pragma unroll
      for (int vt=0;vt<4;vt++)
        #pragma unroll
        for (int r=0;r<4;r++)
          oacc[rg][vt][r] *= al[r];

      #pragma unroll
      for (int t=0;t<4;t++){
        int c = 2*t + (quad>>1);
        us4 pk;
        #pragma unroll
        for (int r=0;r<4;r++) pk[r] = f2bf_fast(sacc[t][r]);
        *(us4*)&Pw[(ln*8 + (c ^ (ln&7)))*8 + (quad&1)*4] = pk;
      }
      asm volatile("s_waitcnt lgkmcnt(0)" ::: "memory");

      __builtin_amdgcn_s_setprio(1);
      #pragma unroll
      for (int s2=0; s2<2; s2++){
        int c = s2*4 + quad;
        bh8 pf = *(const bh8*)(&Pw[(ln*8 + (c ^ (ln&7)))*8]);
        #pragma unroll
        for (int vt=0; vt<4; vt++){
          int vd = vt*16 + ln;
          bh8 vf = *(const bh8*)(&Vc[(vd*8 + (c ^ (ln&7)))*8]);
          oacc[rg][vt] = __builtin_amdgcn_mfma_f32_16x16x32_bf16(pf, vf, oacc[rg][vt], 0,0,0);
        }
      }
      __builtin_amdgcn_s_setprio(0);
      asm volatile("s_waitcnt lgkmcnt(0)" ::: "memory");  // drain before Pw reuse
    }
    __syncthreads();   // prefetch arrived (vmcnt drain overlapped compute); buffers safe
  }

  #pragma unroll
  for (int rg=0; rg<2; rg++){
    float linv = 1.0f / l_i[rg];
    float lb[4];
    #pragma unroll
    for (int r=0;r<4;r++) lb[r] = __shfl(linv, quad*4 + r, 64);
    #pragma unroll
    for (int r=0;r<4;r++){
      #pragma unroll
      for (int vt=0; vt<4; vt++){
        float ov = oacc[rg][vt][r] * lb[r];
        O[(size_t)(b*S_ + q0w + rg*16 + quad*4 + r)*D_ + headoff + vt*16 + ln] = f2bf(ov);
      }
    }
  }
}

extern "C" void kernel_launch(void* const* d_in, const int* in_sizes, int n_in,
                              void* d_out, int out_size, void* d_ws, size_t ws_size,
                              hipStream_t stream){
  const float* q  = (const float*)d_in[0];
  const float* k  = (const float*)d_in[1];
  const float* v  = (const float*)d_in[2];
  const float* Wq = (const float*)d_in[3];
  const float* Wk = (const float*)d_in[4];
  const float* Wv = (const float*)d_in[5];
  const float* Wo = (const float*)d_in[6];
  // d_in[7] = causal mask, statically known -> ignored

  u16* ws  = (u16*)d_ws;
  u16* WT  = ws;                                // 4 x 1M bf16 (Wq*C1, Wk, Wv, Wo)^T
  u16* xa  = WT + (size_t)4*1024*1024;          // q bf16
  u16* xb  = xa + MD_;                          // k bf16 (contiguous after xa)
  u16* Qp  = xb + MD_;                          // Q proj (C1-scaled), later O
  u16* Kp  = Qp + MD_;                          // 8 MB + 4*16 MB = 72 MB ws

  // d_out (2*MD_ u16) doubles as scratch until the final GEMM:
  u16* vb  = (u16*)d_out;                       // v bf16       [0,   MD_)
  u16* VtG = vb + MD_;                          // per-head V^T [MD_, 2*MD_)

  prep_k<<<dim3(16384), 256, 0, stream>>>(q, k, v, Wq, Wk, Wv, Wo, xa, xb, vb, WT);

  gemm8<0><<<dim3(768), 512, 0, stream>>>(xa, vb, WT, Qp, VtG, nullptr);      // Qp, Kp, VtG

  attn_k<<<dim3(B_*H_, S_/128), 256, 0, stream>>>(Qp, Kp, VtG, Qp);           // O over Q

  gemm8<1><<<dim3(256), 512, 0, stream>>>(Qp, nullptr, WT + (size_t)3*1024*1024,
                                          nullptr, nullptr, (float*)d_out);
}

// Round 7
// 326.541 us; speedup vs baseline: 1.3967x; 1.0014x over previous
//
#include <hip/hip_runtime.h>
#include <hip/hip_bf16.h>
#include <stdint.h>

#define B_  4
#define S_  2048
#define D_  1024
#define H_  16
#define DK_ 64
#define M_  (B_*S_)                 // 8192
#define MD_ ((size_t)M_*D_)         // 8388608

typedef unsigned short u16;
typedef unsigned int   u32;
using bh8 = __attribute__((ext_vector_type(8))) short;
using fx4 = __attribute__((ext_vector_type(4))) float;
using us4 = __attribute__((ext_vector_type(4))) unsigned short;

#define C1_ 0.18033688011112042f    // (1/sqrt(64)) * log2(e)

__device__ __forceinline__ u16 f2bf(float f){
  union { float f; u32 u; } v; v.f = f;
  u32 r = v.u + 0x7FFFu + ((v.u >> 16) & 1u);
  return (u16)(r >> 16);
}
__device__ __forceinline__ u16 f2bf_fast(float f){
  union { float f; u32 u; } v; v.f = f;
  return (u16)((v.u + 0x8000u) >> 16);
}
__device__ __forceinline__ float fexp2(float x){
  float r;
  asm("v_exp_f32 %0, %1\n\ts_nop 0" : "=v"(r) : "v"(x));
  return r;
}
// async global->LDS, 16B/lane; LDS dest = wave-uniform base + lane*16
__device__ __forceinline__ void gl16(const void* g, void* l){
  __builtin_amdgcn_global_load_lds(
      (const __attribute__((address_space(1))) unsigned int*)g,
      (__attribute__((address_space(3))) unsigned int*)l, 16, 0, 0);
}

// ---------- fused prep: fp32->bf16 cvt (q,k,v) + 4x W transpose ----------
__global__ __launch_bounds__(256) void prep_k(const float* __restrict__ q,
                                              const float* __restrict__ k,
                                              const float* __restrict__ v,
                                              const float* __restrict__ W0,
                                              const float* __restrict__ W1,
                                              const float* __restrict__ W2,
                                              const float* __restrict__ W3,
                                              u16* __restrict__ dq,
                                              u16* __restrict__ dk,
                                              u16* __restrict__ dv,
                                              u16* __restrict__ WT){
  int id = blockIdx.x;
  int tid = threadIdx.x;
  if (id < 12288){
    int z = id >> 12;
    int i = (id & 4095)*256 + tid;            // n8 = 4096*256 exactly
    const float* in = (z==0)? q : (z==1)? k : v;
    u16* out = (z==0)? dq : (z==1)? dk : dv;
    const float4* p = (const float4*)(in + (size_t)i*8);
    float4 a0 = p[0], a1 = p[1];
    u16 o[8];
    o[0]=f2bf(a0.x); o[1]=f2bf(a0.y); o[2]=f2bf(a0.z); o[3]=f2bf(a0.w);
    o[4]=f2bf(a1.x); o[5]=f2bf(a1.y); o[6]=f2bf(a1.z); o[7]=f2bf(a1.w);
    *(bh8*)(out + (size_t)i*8) = *(bh8*)o;
  } else {
    int id2 = id - 12288;
    int z = id2 >> 10, b2 = id2 & 1023;
    int bx = b2 & 31, by = b2 >> 5;
    const float* in = (z==0)? W0 : (z==1)? W1 : (z==2)? W2 : W3;
    float scale = (z==0)? C1_ : 1.0f;
    u16* o = WT + (size_t)z*1024*1024;
    __shared__ u16 tile[32][33];
    int tx = tid & 31, ty = tid >> 5;         // 32 x 8
    int x0 = bx*32, y0 = by*32;
    #pragma unroll
    for (int j=0;j<32;j+=8) tile[ty+j][tx] = f2bf(in[(size_t)(y0+ty+j)*D_ + x0+tx]*scale);
    __syncthreads();
    #pragma unroll
    for (int j=0;j<32;j+=8) o[(size_t)(x0+ty+j)*D_ + y0+tx] = tile[tx][ty+j];
  }
}

// ---------- unified 8-wave GEMM: 128(M) x 256(N) tile, BK=64 ----------
// (R6-verified, unchanged)
template<int MODE>
__global__ __launch_bounds__(512) void gemm8(const u16* __restrict__ Aqk,
                                             const u16* __restrict__ Av,
                                             const u16* __restrict__ WTb,
                                             u16* __restrict__ Cqk,
                                             u16* __restrict__ VtOut,
                                             float* __restrict__ Cf){
  __shared__ __align__(16) u16 AL[2][128*64];   // 2 x 16 KB
  __shared__ __align__(16) u16 BL[2][256*64];   // 2 x 32 KB

  int hbid = blockIdx.x;
  int xcd = hbid & 7, slot = hbid >> 3;
  int pg  = xcd * (MODE==0 ? 24 : 8) + (slot >> 2);
  int x   = slot & 3;
  int y   = (MODE==0) ? (pg & 63) : pg;
  int z   = (MODE==0) ? (pg >> 6) : 0;

  const u16* A  = (MODE==0 && z==2) ? Av : (Aqk + (size_t)z*MD_);
  const u16* BT = WTb + (size_t)z*1024*1024;
  int tid = threadIdx.x;
  int w = tid >> 6, lane = tid & 63, quad = lane >> 4, ln = lane & 15;
  int wm = w >> 2, wn = w & 3;
  int rowBase = y*128, colBase = x*256;

  auto sA = [&](int buf, int kt, int c){      // c in {0,1}
    int s = c*512 + tid;
    int row = s >> 3, kc = (s & 7) ^ (row & 7);
    gl16(&A[(size_t)(rowBase + row)*D_ + kt*64 + kc*8], &AL[buf][s*8]);
  };
  auto sB = [&](int buf, int kt, int c){      // c in {0..3}
    int s = c*512 + tid;
    int row = s >> 3, kc = (s & 7) ^ (row & 7);
    gl16(&BT[(size_t)(colBase + row)*D_ + kt*64 + kc*8], &BL[buf][s*8]);
  };
  auto ridx = [&](int row, int kc){ return row*64 + ((kc ^ (row & 7))*8); };

  fx4 acc[4][4];
  #pragma unroll
  for (int i=0;i<4;i++)
    #pragma unroll
    for (int j=0;j<4;j++) acc[i][j] = (fx4){0.f,0.f,0.f,0.f};

  sA(0,0,0); sA(0,0,1); sB(0,0,0); sB(0,0,1); sB(0,0,2); sB(0,0,3);
  sB(1,1,0); sB(1,1,1); sB(1,1,2);
  asm volatile("s_waitcnt vmcnt(3)" ::: "memory");
  __builtin_amdgcn_s_barrier();

  for (int it = 0; it < 8; ++it){
    int t = 2*it;
    bool h2 = (t+2 < 16), h3 = (t+3 < 16);
    #pragma unroll
    for (int half = 0; half < 2; ++half){     // buf == half (t even)
      const u16* Ab = &AL[half][0];
      const u16* Bb = &BL[half][0];

      // ---- q0 phase ----
      bh8 bfr[4][2], af0[2][2], af1[2][2];
      #pragma unroll
      for (int n=0;n<4;n++)
        #pragma unroll
        for (int ks=0;ks<2;ks++)
          bfr[n][ks] = *(const bh8*)(&Bb[ridx(wn*64 + n*16 + ln, ks*4+quad)]);
      #pragma unroll
      for (int mi=0;mi<2;mi++)
        #pragma unroll
        for (int ks=0;ks<2;ks++)
          af0[mi][ks] = *(const bh8*)(&Ab[ridx(wm*64 + mi*16 + ln, ks*4+quad)]);
      #pragma unroll
      for (int mi=0;mi<2;mi++)
        #pragma unroll
        for (int ks=0;ks<2;ks++)
          af1[mi][ks] = *(const bh8*)(&Ab[ridx(wm*64 + 32 + mi*16 + ln, ks*4+quad)]);

      if (half == 0){
        sB(1, t+1, 3); sA(1, t+1, 0); sA(1, t+1, 1);
      } else if (h2){
        sB(0, t+2, 3); sA(0, t+2, 0); sA(0, t+2, 1);
      }
      __builtin_amdgcn_s_barrier();
      asm volatile("s_waitcnt lgkmcnt(4)" ::: "memory");   // bfr+af0 done
      __builtin_amdgcn_s_setprio(1);
      #pragma unroll
      for (int mi=0;mi<2;mi++)
        #pragma unroll
        for (int n=0;n<4;n++)
          #pragma unroll
          for (int ks=0;ks<2;ks++)
            acc[mi][n] = __builtin_amdgcn_mfma_f32_16x16x32_bf16(
                            af0[mi][ks], bfr[n][ks], acc[mi][n], 0,0,0);
      __builtin_amdgcn_s_setprio(0);
      __builtin_amdgcn_s_barrier();

      // ---- q1 phase ----
      if (half == 0){
        if (h2){ sB(0, t+2, 0); sB(0, t+2, 1); sB(0, t+2, 2); }
        if (h2) asm volatile("s_waitcnt vmcnt(3)" ::: "memory");
        else    asm volatile("s_waitcnt vmcnt(0)" ::: "memory");
      } else {
        if (h3){ sB(1, t+3, 0); sB(1, t+3, 1); sB(1, t+3, 2); }
        if (h3) asm volatile("s_waitcnt vmcnt(3)" ::: "memory");
        else    asm volatile("s_waitcnt vmcnt(0)" ::: "memory");
      }
      __builtin_amdgcn_s_barrier();
      asm volatile("s_waitcnt lgkmcnt(0)" ::: "memory");   // af1 done
      __builtin_amdgcn_s_setprio(1);
      #pragma unroll
      for (int mi=0;mi<2;mi++)
        #pragma unroll
        for (int n=0;n<4;n++)
          #pragma unroll
          for (int ks=0;ks<2;ks++)
            acc[2+mi][n] = __builtin_amdgcn_mfma_f32_16x16x32_bf16(
                              af1[mi][ks], bfr[n][ks], acc[2+mi][n], 0,0,0);
      __builtin_amdgcn_s_setprio(0);
      __builtin_amdgcn_s_barrier();
    }
  }

  #pragma unroll
  for (int m=0;m<4;m++){
    int row0 = rowBase + wm*64 + m*16 + quad*4;
    #pragma unroll
    for (int n=0;n<4;n++){
      int col = colBase + wn*64 + n*16 + ln;
      if (MODE == 1){
        #pragma unroll
        for (int r=0;r<4;r++)
          Cf[(size_t)(row0 + r)*D_ + col] = acc[m][n][r];
      } else if (z == 2){
        int bb = row0 >> 11, tok = row0 & (S_-1);
        int hh = col >> 6,  vd  = col & 63;
        us4 pk;
        #pragma unroll
        for (int r=0;r<4;r++) pk[r] = f2bf(acc[m][n][r]);
        *(us4*)&VtOut[((size_t)((bb*16+hh)*64+vd))*S_ + tok] = pk;
      } else {
        #pragma unroll
        for (int r=0;r<4;r++)
          (Cqk + (size_t)z*MD_)[(size_t)(row0 + r)*D_ + col] = f2bf(acc[m][n][r]);
      }
    }
  }
}

// ---------- flash attention, causal ----------
// R5 swapped-QK structure +:
// (a) conflict-free P layout: 16 halfslots (8B)/row, phys hs = (4t+quad)
//     ^ (ln&14) -> each b64 write instr spreads 64 lanes over all 16
//     bank-pairs, 4 lanes each (b64 minimum; old layout used 16 of 32
//     banks -> measured 16 extra cyc/write, 2.23M/dispatch). Read: 16B
//     chunk pm = c ^ ((ln>>1)&7); ln&14 preserves bit0 so the two
//     logical halves stay adjacent+ordered.
// (b) defer-max (T13, THR=8 in log2 domain): skip alpha exp + 4 shfl +
//     16 oacc mults + l-scale when __any(mloc > m+8) is false (uniform
//     branch). P bounded by 2^8 -> safe in bf16.
// (c) setprio(1) around QK MFMA cluster (was PV-only).
__global__ __launch_bounds__(256) void attn_k(const u16* __restrict__ Q,
                                              const u16* __restrict__ Kp,
                                              const u16* __restrict__ VtG,
                                              u16* __restrict__ O){
  __shared__ __align__(16) u16 Kt[2][64*64];    // 2 x 8 KB
  __shared__ __align__(16) u16 Vt[2][64*64];    // 2 x 8 KB
  __shared__ __align__(16) u16 Pb[4*16*64];     // 8 KB

  int bh = blockIdx.x; int b = bh>>4, h = bh&15;
  int qt = (int)gridDim.y - 1 - (int)blockIdx.y;   // heavy dispatch-waves first
  int tid = threadIdx.x;
  int w = tid >> 6, lane = tid & 63, quad = lane >> 4, ln = lane & 15;
  int q0w = qt*128 + w*32;
  size_t headoff = (size_t)h*DK_;

  bh8 qf[2][2];
  #pragma unroll
  for (int rg=0; rg<2; rg++){
    const u16* qp = Q + (size_t)(b*S_ + q0w + rg*16 + ln)*D_ + headoff + quad*8;
    qf[rg][0] = *(const bh8*)qp;
    qf[rg][1] = *(const bh8*)(qp + 32);
  }

  float m_i[2], l_i[2];
  fx4 oacc[2][4];
  #pragma unroll
  for (int rg=0; rg<2; rg++){
    m_i[rg] = -3e38f; l_i[rg] = 0.f;
    #pragma unroll
    for (int r=0;r<4;r++) oacc[rg][r] = (fx4){0.f,0.f,0.f,0.f};
  }

  auto stage = [&](int k0, int bi){
    #pragma unroll
    for (int i=0;i<2;i++){
      int s = i*256 + tid;
      int n = s >> 3, kc = (s & 7) ^ (n & 7);
      gl16(&Kp[(size_t)(b*S_ + k0 + n)*D_ + headoff + kc*8], &Kt[bi][s*8]);
    }
    #pragma unroll
    for (int i=0;i<2;i++){
      int s = i*256 + tid;
      int vd = s >> 3, c = (s & 7) ^ (vd & 7);
      gl16(&VtG[(size_t)(bh*64 + vd)*S_ + k0 + c*8], &Vt[bi][s*8]);
    }
  };

  u16* Pw = &Pb[w*16*64];
  int ntiles = 2*qt + 2;           // k-tiles of 64 covering [0, (qt+1)*128)

  stage(0, 0);
  __syncthreads();                 // drain prologue staging

  for (int kt=0; kt<ntiles; kt++){
    int cur = kt & 1;
    if (kt+1 < ntiles) stage((kt+1)*64, cur^1);   // prefetch, no wait
    const u16* Kc = Kt[cur];
    const u16* Vc = Vt[cur];
    int k0 = kt*64;
    bool diag = (kt >= 2*qt);      // last two tiles straddle the diagonal

    #pragma unroll
    for (int rg=0; rg<2; rg++){
      // QK^T swapped: sacc[t] = K_frag[t] x Q_frag -> S^T
      // lane (quad,ln): keys k0 + t*16 + quad*4 + r, query q0w + rg*16 + ln
      fx4 sacc[4];
      __builtin_amdgcn_s_setprio(1);
      #pragma unroll
      for (int t=0;t<4;t++){
        int n = t*16 + ln;
        bh8 kf0 = *(const bh8*)(&Kc[(n*8 + ( quad    ^ (ln&7)))*8]);
        bh8 kf1 = *(const bh8*)(&Kc[(n*8 + ((4+quad) ^ (ln&7)))*8]);
        fx4 zz = (fx4){0.f,0.f,0.f,0.f};
        zz = __builtin_amdgcn_mfma_f32_16x16x32_bf16(kf0, qf[rg][0], zz, 0,0,0);
        zz = __builtin_amdgcn_mfma_f32_16x16x32_bf16(kf1, qf[rg][1], zz, 0,0,0);
        sacc[t] = zz;
      }
      __builtin_amdgcn_s_setprio(0);

      int qg = q0w + rg*16 + ln;
      if (diag){
        #pragma unroll
        for (int t=0;t<4;t++){
          #pragma unroll
          for (int r=0;r<4;r++){
            int kg = k0 + t*16 + quad*4 + r;
            sacc[t][r] = (kg <= qg) ? sacc[t][r] : -3e38f;
          }
        }
      }

      // row reduce: in-register tree + 2 shfl
      float tm[4];
      #pragma unroll
      for (int t=0;t<4;t++)
        tm[t] = fmaxf(fmaxf(sacc[t][0], sacc[t][1]), fmaxf(sacc[t][2], sacc[t][3]));
      float mloc = fmaxf(fmaxf(tm[0], tm[1]), fmaxf(tm[2], tm[3]));
      mloc = fmaxf(mloc, __shfl_xor(mloc, 16, 64));
      mloc = fmaxf(mloc, __shfl_xor(mloc, 32, 64));

      // defer-max: rescale only when the tile max grew past THR=8 (log2)
      if (__any(mloc > m_i[rg] + 8.0f)){
        float mn = fmaxf(m_i[rg], mloc);
        float alpha = fexp2(m_i[rg] - mn);
        m_i[rg] = mn;
        l_i[rg] *= alpha;
        float al[4];
        #pragma unroll
        for (int r=0;r<4;r++) al[r] = __shfl(alpha, quad*4 + r, 64);
        #pragma unroll
        for (int vt=0;vt<4;vt++)
          #pragma unroll
          for (int r=0;r<4;r++)
            oacc[rg][vt][r] *= al[r];
      }
      float mn = m_i[rg];

      float ts[4];
      #pragma unroll
      for (int t=0;t<4;t++){
        #pragma unroll
        for (int r=0;r<4;r++) sacc[t][r] = fexp2(sacc[t][r] - mn);
        ts[t] = (sacc[t][0] + sacc[t][1]) + (sacc[t][2] + sacc[t][3]);
      }
      float rs = (ts[0] + ts[1]) + (ts[2] + ts[3]);
      rs += __shfl_xor(rs, 16, 64);
      rs += __shfl_xor(rs, 32, 64);
      l_i[rg] += rs;

      // P^T -> P: lane holds keys 4*(4t+quad)+{0..3} of query row ln;
      // phys halfslot hs = (4t+quad) ^ (ln&14) -> all 16 bank-pairs hit,
      // 4 lanes each (b64 minimum)
      #pragma unroll
      for (int t=0;t<4;t++){
        int hs = (t*4 + quad) ^ (ln & 14);
        us4 pk;
        #pragma unroll
        for (int r=0;r<4;r++) pk[r] = f2bf_fast(sacc[t][r]);
        *(us4*)&Pw[ln*64 + hs*4] = pk;
      }
      asm volatile("s_waitcnt lgkmcnt(0)" ::: "memory");

      // PV: 64 keys in 2 chunks, vdim in 4 subtiles
      __builtin_amdgcn_s_setprio(1);
      #pragma unroll
      for (int s2=0; s2<2; s2++){
        int c = s2*4 + quad;
        int pm = c ^ ((ln>>1) & 7);
        bh8 pf = *(const bh8*)(&Pw[ln*64 + pm*8]);
        #pragma unroll
        for (int vt=0; vt<4; vt++){
          int vd = vt*16 + ln;
          bh8 vf = *(const bh8*)(&Vc[(vd*8 + (c ^ (ln&7)))*8]);
          oacc[rg][vt] = __builtin_amdgcn_mfma_f32_16x16x32_bf16(pf, vf, oacc[rg][vt], 0,0,0);
        }
      }
      __builtin_amdgcn_s_setprio(0);
      asm volatile("s_waitcnt lgkmcnt(0)" ::: "memory");  // drain before Pw reuse
    }
    __syncthreads();   // prefetch arrived (vmcnt drain overlapped compute); buffers safe
  }

  // epilogue: O = acc / l ; 1/l broadcast to oacc rows q=quad*4+r
  #pragma unroll
  for (int rg=0; rg<2; rg++){
    float linv = 1.0f / l_i[rg];
    float lb[4];
    #pragma unroll
    for (int r=0;r<4;r++) lb[r] = __shfl(linv, quad*4 + r, 64);
    #pragma unroll
    for (int r=0;r<4;r++){
      #pragma unroll
      for (int vt=0; vt<4; vt++){
        float ov = oacc[rg][vt][r] * lb[r];
        O[(size_t)(b*S_ + q0w + rg*16 + quad*4 + r)*D_ + headoff + vt*16 + ln] = f2bf(ov);
      }
    }
  }
}

extern "C" void kernel_launch(void* const* d_in, const int* in_sizes, int n_in,
                              void* d_out, int out_size, void* d_ws, size_t ws_size,
                              hipStream_t stream){
  const float* q  = (const float*)d_in[0];
  const float* k  = (const float*)d_in[1];
  const float* v  = (const float*)d_in[2];
  const float* Wq = (const float*)d_in[3];
  const float* Wk = (const float*)d_in[4];
  const float* Wv = (const float*)d_in[5];
  const float* Wo = (const float*)d_in[6];
  // d_in[7] = causal mask, statically known -> ignored

  u16* ws  = (u16*)d_ws;
  u16* WT  = ws;                                // 4 x 1M bf16 (Wq*C1, Wk, Wv, Wo)^T
  u16* xa  = WT + (size_t)4*1024*1024;          // q bf16
  u16* xb  = xa + MD_;                          // k bf16 (contiguous after xa)
  u16* Qp  = xb + MD_;                          // Q proj (C1-scaled), later O
  u16* Kp  = Qp + MD_;                          // 8 MB + 4*16 MB = 72 MB ws

  // d_out (2*MD_ u16) doubles as scratch until the final GEMM:
  u16* vb  = (u16*)d_out;                       // v bf16       [0,   MD_)
  u16* VtG = vb + MD_;                          // per-head V^T [MD_, 2*MD_)

  prep_k<<<dim3(16384), 256, 0, stream>>>(q, k, v, Wq, Wk, Wv, Wo, xa, xb, vb, WT);

  gemm8<0><<<dim3(768), 512, 0, stream>>>(xa, vb, WT, Qp, VtG, nullptr);      // Qp, Kp, VtG

  attn_k<<<dim3(B_*H_, S_/128), 256, 0, stream>>>(Qp, Kp, VtG, Qp);           // O over Q

  gemm8<1><<<dim3(256), 512, 0, stream>>>(Qp, nullptr, WT + (size_t)3*1024*1024,
                                          nullptr, nullptr, (float*)d_out);
}